// Round 1
// baseline (465.699 us; speedup 1.0000x reference)
//
#include <hip/hip_runtime.h>
#include <hip/hip_fp16.h>

#define PI_F 3.14159265358979323846f

__device__ __forceinline__ float2 cmul(float2 a, float2 b) {
    return make_float2(a.x*b.x - a.y*b.y, a.x*b.y + a.y*b.x);
}

__device__ __forceinline__ void apply_gate(float2& a0, float2& a1,
                                           float2 u00, float2 u01, float2 u10, float2 u11) {
    float2 n0 = make_float2(
        u00.x*a0.x - u00.y*a0.y + u01.x*a1.x - u01.y*a1.y,
        u00.x*a0.y + u00.y*a0.x + u01.x*a1.y + u01.y*a1.x);
    float2 n1 = make_float2(
        u10.x*a0.x - u10.y*a0.y + u11.x*a1.x - u11.y*a1.y,
        u10.x*a0.y + u10.y*a0.x + u11.x*a1.y + u11.y*a1.x);
    a0 = n0; a1 = n1;
}

// ---------------- K1: encoder MLP -> U3 matrices ----------------
__global__ __launch_bounds__(128) void k_encoder(
        const float* __restrict__ x, const float* __restrict__ W1,
        const float* __restrict__ b1, const float* __restrict__ W2,
        const float* __restrict__ b2, const float* __restrict__ scaling,
        float2* __restrict__ v0, float2* __restrict__ U1) {
    __shared__ float xr[64];
    __shared__ float h[128];
    __shared__ float ang[96];
    const int b = blockIdx.x, t = threadIdx.x;
    if (t < 64) xr[t] = x[b*64 + t];
    __syncthreads();
    {
        float acc = b1[t];
        #pragma unroll 8
        for (int f = 0; f < 64; ++f) acc = fmaf(xr[f], W1[f*128 + t], acc);
        h[t] = fmaxf(acc, 0.f);
    }
    __syncthreads();
    if (t < 96) {
        float acc = b2[t];
        #pragma unroll 8
        for (int f = 0; f < 128; ++f) acc = fmaf(h[f], W2[f*96 + t], acc);
        int q = (t/3) & 15;
        ang[t] = tanhf(acc) * scaling[q] * PI_F;
    }
    __syncthreads();
    if (t < 32) {
        int l = t >> 4, q = t & 15;
        const float* a = ang + l*48 + q*3;
        float st, ct, sp, cp, sl, cl;
        sincosf(a[0]*0.5f, &st, &ct);
        sincosf(a[1]*0.5f, &sp, &cp);
        sincosf(a[2]*0.5f, &sl, &cl);
        // A = Ry@Rx ; U = Rz@A
        float2 A00 = make_float2( cp*ct,  sp*st);
        float2 A01 = make_float2(-sp*ct, -cp*st);
        float2 A10 = make_float2( sp*ct, -cp*st);
        float2 A11 = make_float2( cp*ct, -sp*st);
        float2 e0 = make_float2(cl, -sl), e1 = make_float2(cl, sl);
        if (l == 0) {
            float2* v = v0 + (b*16 + q)*2;   // U|0> = column 0
            v[0] = cmul(e0, A00);
            v[1] = cmul(e1, A10);
        } else {
            float2* u = U1 + (b*16 + q)*4;
            u[0] = cmul(e0, A00); u[1] = cmul(e0, A01);
            u[2] = cmul(e1, A10); u[3] = cmul(e1, A11);
        }
    }
}

// ---------------- K2: product state (layer0 + CNOT perm) + layer1 gates on qubits 3..15 ----
// block = (b, chunk c of 8192 amps). LDS chunk, 13 in-LDS sweeps, write half2 state.
__global__ __launch_bounds__(512) void k_sim1(
        const float2* __restrict__ v0, const float2* __restrict__ U1,
        unsigned int* __restrict__ state) {
    __shared__ float2 amp[8192];   // 64 KB
    const int b = blockIdx.x >> 3, c = blockIdx.x & 7;
    const int tid = threadIdx.x;
    const float2* v = v0 + b*32;   // [16 qubits][2]
    // initial amp at post-CNOT index z: prod_q v_q[w_q(z)]
    // bit_p(w)=z_p^z_{p+1} (p<=13); bit14=z14^z15^z0; bit15=z15^z0
    const int zbase = c*8192 + tid*16;
    const int zz = zbase ^ (zbase >> 1);
    float2 F = make_float2(1.f, 0.f);
    #pragma unroll
    for (int p = 4; p <= 13; ++p)
        F = cmul(F, v[(15-p)*2 + ((zz>>p)&1)]);
    const int c1 = (c>>1)&1, c2 = c>>2;
    float2 H0 = cmul(cmul(F, v[2 + (c1^c2)]),   v[c2]);      // z0 = 0
    float2 H1 = cmul(cmul(F, v[2 + (c1^c2^1)]), v[c2^1]);    // z0 = 1
    const int t4 = tid & 1;  // z bit 4
    #pragma unroll
    for (int i = 0; i < 16; ++i) {
        int i0 = i&1, i1 = (i>>1)&1, i2 = (i>>2)&1, i3 = i>>3;
        float2 lo = cmul(cmul(v[30 + (i0^i1)], v[28 + (i1^i2)]),
                         cmul(v[26 + (i2^i3)], v[24 + (i3^t4)]));
        amp[tid*16 + i] = cmul(lo, i0 ? H1 : H0);
    }
    __syncthreads();
    // 13 sweeps: bit p <-> qubit 15-p
    for (int p = 0; p < 13; ++p) {
        const int q = 15 - p;
        const float2* u = U1 + (b*16 + q)*4;
        const float2 u00 = u[0], u01 = u[1], u10 = u[2], u11 = u[3];
        const int s = 1 << p;
        #pragma unroll
        for (int it = 0; it < 8; ++it) {
            int pp = tid + 512*it;
            int i0 = ((pp >> p) << (p+1)) | (pp & (s-1));
            int i1 = i0 + s;
            float2 a0 = amp[i0], a1 = amp[i1];
            apply_gate(a0, a1, u00, u01, u10, u11);
            amp[i0] = a0; amp[i1] = a1;
        }
        __syncthreads();
    }
    const size_t base = (size_t)b*65536 + c*8192;
    #pragma unroll
    for (int it = 0; it < 16; ++it) {
        int idx = tid + 512*it;
        float2 a = amp[idx];
        __half2 hv = __floats2half2_rn(a.x, a.y);
        unsigned int u; __builtin_memcpy(&u, &hv, 4);
        state[base + idx] = u;
    }
}

// ---------------- K3: layer1 gates on qubits 0..2 (bits 13..15) + probs (in place) ----
__global__ __launch_bounds__(256) void k_sim2(
        const float2* __restrict__ U1, unsigned int* __restrict__ state) {
    const int b = blockIdx.x >> 3, jc = blockIdx.x & 7;
    const int tid = threadIdx.x;
    const float2* ub = U1 + b*64;
    const float2 g2a = ub[8],  g2b = ub[9],  g2c = ub[10], g2d = ub[11]; // qubit2 -> k bit0
    const float2 g1a = ub[4],  g1b = ub[5],  g1c = ub[6],  g1d = ub[7];  // qubit1 -> k bit1
    const float2 g0a = ub[0],  g0b = ub[1],  g0c = ub[2],  g0d = ub[3];  // qubit0 -> k bit2
    const size_t sb = (size_t)b*65536;
    for (int it = 0; it < 4; ++it) {
        const int j = jc*1024 + tid + 256*it;
        float2 a[8];
        #pragma unroll
        for (int k = 0; k < 8; ++k) {
            unsigned int u = state[sb + j + (k<<13)];
            __half2 hv; __builtin_memcpy(&hv, &u, 4);
            float2 f = __half22float2(hv);
            a[k] = make_float2(f.x, f.y);
        }
        apply_gate(a[0], a[1], g2a, g2b, g2c, g2d);
        apply_gate(a[2], a[3], g2a, g2b, g2c, g2d);
        apply_gate(a[4], a[5], g2a, g2b, g2c, g2d);
        apply_gate(a[6], a[7], g2a, g2b, g2c, g2d);
        apply_gate(a[0], a[2], g1a, g1b, g1c, g1d);
        apply_gate(a[1], a[3], g1a, g1b, g1c, g1d);
        apply_gate(a[4], a[6], g1a, g1b, g1c, g1d);
        apply_gate(a[5], a[7], g1a, g1b, g1c, g1d);
        apply_gate(a[0], a[4], g0a, g0b, g0c, g0d);
        apply_gate(a[1], a[5], g0a, g0b, g0c, g0d);
        apply_gate(a[2], a[6], g0a, g0b, g0c, g0d);
        apply_gate(a[3], a[7], g0a, g0b, g0c, g0d);
        #pragma unroll
        for (int k = 0; k < 8; ++k) {
            float pr = a[k].x*a[k].x + a[k].y*a[k].y;
            state[sb + j + (k<<13)] = __float_as_uint(pr);
        }
    }
}

// ---------------- K4: split-K fp32 GEMM: partial[kc] = probs[:,kc*256:+256] @ Wd1[...] ----
__global__ __launch_bounds__(256, 1) void k_gemm1(
        const float* __restrict__ probs, const float* __restrict__ Wd1,
        float* __restrict__ partial) {
    __shared__ float Als[16][256];   // [kk][m]
    __shared__ float Bls[16][256];   // [kk][n]
    const int kc = blockIdx.x;
    const int tid = threadIdx.x;
    const int tm = tid & 15, tn = tid >> 4;
    const int m0 = tm*16, n0 = tn*16;
    const int kbase = kc*256;
    float acc[16][16];
    #pragma unroll
    for (int i = 0; i < 16; ++i)
        #pragma unroll
        for (int j = 0; j < 16; ++j) acc[i][j] = 0.f;
    float4 pa[4], pb[4];
    #pragma unroll
    for (int r = 0; r < 4; ++r) {
        int f4 = tid + r*256;
        int am = f4 >> 2, ak4 = (f4 & 3)*4;
        pa[r] = *(const float4*)(probs + (size_t)am*65536 + kbase + ak4);
        int bk = f4 >> 6, bn4 = (f4 & 63)*4;
        pb[r] = *(const float4*)(Wd1 + (size_t)(kbase + bk)*256 + bn4);
    }
    for (int ks = 0; ks < 256; ks += 16) {
        __syncthreads();
        #pragma unroll
        for (int r = 0; r < 4; ++r) {
            int f4 = tid + r*256;
            int am = f4 >> 2, ak4 = (f4 & 3)*4;
            Als[ak4+0][am] = pa[r].x; Als[ak4+1][am] = pa[r].y;
            Als[ak4+2][am] = pa[r].z; Als[ak4+3][am] = pa[r].w;
            int bk = f4 >> 6, bn4 = (f4 & 63)*4;
            *(float4*)&Bls[bk][bn4] = pb[r];
        }
        __syncthreads();
        if (ks + 16 < 256) {
            #pragma unroll
            for (int r = 0; r < 4; ++r) {
                int f4 = tid + r*256;
                int am = f4 >> 2, ak4 = (f4 & 3)*4;
                pa[r] = *(const float4*)(probs + (size_t)am*65536 + kbase + ks + 16 + ak4);
                int bk = f4 >> 6, bn4 = (f4 & 63)*4;
                pb[r] = *(const float4*)(Wd1 + (size_t)(kbase + ks + 16 + bk)*256 + bn4);
            }
        }
        #pragma unroll
        for (int kk = 0; kk < 16; ++kk) {
            float av[16], bv[16];
            #pragma unroll
            for (int i4 = 0; i4 < 4; ++i4) {
                *(float4*)&av[i4*4] = *(const float4*)&Als[kk][m0 + i4*4];
                *(float4*)&bv[i4*4] = *(const float4*)&Bls[kk][n0 + i4*4];
            }
            #pragma unroll
            for (int i = 0; i < 16; ++i)
                #pragma unroll
                for (int j = 0; j < 16; ++j)
                    acc[i][j] = fmaf(av[i], bv[j], acc[i][j]);
        }
    }
    float* outp = partial + (size_t)kc*65536;
    #pragma unroll
    for (int i = 0; i < 16; ++i)
        #pragma unroll
        for (int j4 = 0; j4 < 4; ++j4)
            *(float4*)(outp + (m0+i)*256 + n0 + j4*4) = *(float4*)&acc[i][j4*4];
}

// ---------------- K5: reduce partials + bias + relu + final GEMV + bias + relu ----
__global__ __launch_bounds__(256) void k_final(
        const float* __restrict__ partial, const float* __restrict__ bd1,
        const float* __restrict__ Wd2, const float* __restrict__ bd2,
        float* __restrict__ out) {
    __shared__ float row[256];
    const int m = blockIdx.x, t = threadIdx.x;
    float acc = 0.f;
    const float* p = partial + (size_t)m*256 + t;
    #pragma unroll 8
    for (int kc = 0; kc < 256; ++kc) acc += p[(size_t)kc*65536];
    row[t] = fmaxf(acc + bd1[t], 0.f);
    __syncthreads();
    if (t < 64) {
        float o = bd2[t];
        #pragma unroll 8
        for (int n = 0; n < 256; ++n) o = fmaf(row[n], Wd2[n*64 + t], o);
        out[m*64 + t] = fmaxf(o, 0.f);
    }
}

extern "C" void kernel_launch(void* const* d_in, const int* in_sizes, int n_in,
                              void* d_out, int out_size, void* d_ws, size_t ws_size,
                              hipStream_t stream) {
    const float* x       = (const float*)d_in[0];
    const float* W1      = (const float*)d_in[1];
    const float* b1      = (const float*)d_in[2];
    const float* W2      = (const float*)d_in[3];
    const float* b2      = (const float*)d_in[4];
    const float* scaling = (const float*)d_in[5];
    const float* Wd1     = (const float*)d_in[6];
    const float* bd1     = (const float*)d_in[7];
    const float* Wd2     = (const float*)d_in[8];
    const float* bd2     = (const float*)d_in[9];
    float* out = (float*)d_out;

    char* ws = (char*)d_ws;
    float2* v0 = (float2*)(ws + 0);                       //  64 KB
    float2* U1 = (float2*)(ws + 65536);                   // 128 KB
    unsigned int* state = (unsigned int*)(ws + (1u<<20)); //  64 MB (half2 -> fp32 probs in place)
    float* partial = (float*)(ws + (1u<<20) + (size_t)64*1024*1024); // 64 MB

    hipLaunchKernelGGL(k_encoder, dim3(256), dim3(128), 0, stream,
                       x, W1, b1, W2, b2, scaling, v0, U1);
    hipLaunchKernelGGL(k_sim1, dim3(2048), dim3(512), 0, stream, v0, U1, state);
    hipLaunchKernelGGL(k_sim2, dim3(2048), dim3(256), 0, stream, U1, state);
    hipLaunchKernelGGL(k_gemm1, dim3(256), dim3(256), 0, stream,
                       (const float*)state, Wd1, partial);
    hipLaunchKernelGGL(k_final, dim3(256), dim3(256), 0, stream,
                       partial, bd1, Wd2, bd2, out);
}

// Round 2
// 275.953 us; speedup vs baseline: 1.6876x; 1.6876x over previous
//
#include <hip/hip_runtime.h>
#include <hip/hip_fp16.h>

#define PI_F 3.14159265358979323846f
#define KDIM 65536

typedef __attribute__((ext_vector_type(8))) __bf16 bf16x8;
typedef __attribute__((ext_vector_type(16))) float f32x16;

__device__ __forceinline__ float2 cmul(float2 a, float2 b) {
    return make_float2(a.x*b.x - a.y*b.y, a.x*b.y + a.y*b.x);
}

__device__ __forceinline__ void apply_gate(float2& a0, float2& a1,
                                           float2 u00, float2 u01, float2 u10, float2 u11) {
    float2 n0 = make_float2(
        u00.x*a0.x - u00.y*a0.y + u01.x*a1.x - u01.y*a1.y,
        u00.x*a0.y + u00.y*a0.x + u01.x*a1.y + u01.y*a1.x);
    float2 n1 = make_float2(
        u10.x*a0.x - u10.y*a0.y + u11.x*a1.x - u11.y*a1.y,
        u10.x*a0.y + u10.y*a0.x + u11.x*a1.y + u11.y*a1.x);
    a0 = n0; a1 = n1;
}

__device__ __forceinline__ unsigned f2bf_rn(float x) {
    unsigned u = __float_as_uint(x);
    return (u + 0x7fffu + ((u >> 16) & 1u)) >> 16;
}

union FragU { int4 i4; bf16x8 v; };
__device__ __forceinline__ bf16x8 mk_frag(int a, int b, int c, int d) {
    FragU u; u.i4 = make_int4(a, b, c, d); return u.v;
}

// async global->LDS, 16B per lane; LDS dest is wave-uniform base + lane*16
__device__ __forceinline__ void gll16(const void* g, void* l) {
    __builtin_amdgcn_global_load_lds(
        (const __attribute__((address_space(1))) void*)g,
        (__attribute__((address_space(3))) void*)l, 16, 0, 0);
}

// ---------------- K1: encoder MLP -> U3 matrices ----------------
__global__ __launch_bounds__(128) void k_encoder(
        const float* __restrict__ x, const float* __restrict__ W1,
        const float* __restrict__ b1, const float* __restrict__ W2,
        const float* __restrict__ b2, const float* __restrict__ scaling,
        float2* __restrict__ v0, float2* __restrict__ U1) {
    __shared__ float xr[64];
    __shared__ float h[128];
    __shared__ float ang[96];
    const int b = blockIdx.x, t = threadIdx.x;
    if (t < 64) xr[t] = x[b*64 + t];
    __syncthreads();
    {
        float acc = b1[t];
        #pragma unroll 8
        for (int f = 0; f < 64; ++f) acc = fmaf(xr[f], W1[f*128 + t], acc);
        h[t] = fmaxf(acc, 0.f);
    }
    __syncthreads();
    if (t < 96) {
        float acc = b2[t];
        #pragma unroll 8
        for (int f = 0; f < 128; ++f) acc = fmaf(h[f], W2[f*96 + t], acc);
        int q = (t/3) & 15;
        ang[t] = tanhf(acc) * scaling[q] * PI_F;
    }
    __syncthreads();
    if (t < 32) {
        int l = t >> 4, q = t & 15;
        const float* a = ang + l*48 + q*3;
        float st, ct, sp, cp, sl, cl;
        sincosf(a[0]*0.5f, &st, &ct);
        sincosf(a[1]*0.5f, &sp, &cp);
        sincosf(a[2]*0.5f, &sl, &cl);
        float2 A00 = make_float2( cp*ct,  sp*st);
        float2 A01 = make_float2(-sp*ct, -cp*st);
        float2 A10 = make_float2( sp*ct, -cp*st);
        float2 A11 = make_float2( cp*ct, -sp*st);
        float2 e0 = make_float2(cl, -sl), e1 = make_float2(cl, sl);
        if (l == 0) {
            float2* v = v0 + (b*16 + q)*2;
            v[0] = cmul(e0, A00);
            v[1] = cmul(e1, A10);
        } else {
            float2* u = U1 + (b*16 + q)*4;
            u[0] = cmul(e0, A00); u[1] = cmul(e0, A01);
            u[2] = cmul(e1, A10); u[3] = cmul(e1, A11);
        }
    }
}

// ---------------- K2: product state + layer1 gates on qubits 3..15 ----------------
// Register gates for idx bits 0-3 (qubits 15..12) and bits 9-12 (qubits 6..3);
// only 5 LDS sweeps (bits 4-8 -> qubits 11..7).
__global__ __launch_bounds__(512) void k_sim1(
        const float2* __restrict__ v0, const float2* __restrict__ U1,
        unsigned int* __restrict__ state) {
    __shared__ float2 amp[8192];   // 64 KB
    const int b = blockIdx.x >> 3, c = blockIdx.x & 7;
    const int tid = threadIdx.x;
    const float2* v = v0 + b*32;
    const float2* ub = U1 + b*64;
    const int zbase = c*8192 + tid*16;
    const int zz = zbase ^ (zbase >> 1);
    float2 F = make_float2(1.f, 0.f);
    #pragma unroll
    for (int p = 4; p <= 13; ++p)
        F = cmul(F, v[(15-p)*2 + ((zz>>p)&1)]);
    const int c1 = (c>>1)&1, c2 = c>>2;
    float2 H0 = cmul(cmul(F, v[2 + (c1^c2)]),   v[c2]);      // z0 = 0
    float2 H1 = cmul(cmul(F, v[2 + (c1^c2^1)]), v[c2^1]);    // z0 = 1
    const int t4 = tid & 1;
    float2 a[16];
    #pragma unroll
    for (int i = 0; i < 16; ++i) {
        int i0 = i&1, i1 = (i>>1)&1, i2 = (i>>2)&1, i3 = i>>3;
        float2 lo = cmul(cmul(v[30 + (i0^i1)], v[28 + (i1^i2)]),
                         cmul(v[26 + (i2^i3)], v[24 + (i3^t4)]));
        a[i] = cmul(lo, i0 ? H1 : H0);
    }
    // register gates: idx bit p <-> qubit 15-p, p = 0..3
    #pragma unroll
    for (int p = 0; p < 4; ++p) {
        const float2* u = ub + (15-p)*4;
        float2 u00 = u[0], u01 = u[1], u10 = u[2], u11 = u[3];
        #pragma unroll
        for (int i = 0; i < 16; ++i)
            if (!(i & (1<<p)))
                apply_gate(a[i], a[i | (1<<p)], u00, u01, u10, u11);
    }
    #pragma unroll
    for (int i = 0; i < 16; ++i) amp[tid*16 + i] = a[i];
    __syncthreads();
    // LDS sweeps p = 4..8 (qubits 11..7)
    for (int p = 4; p <= 8; ++p) {
        const int q = 15 - p;
        const float2* u = ub + q*4;
        const float2 u00 = u[0], u01 = u[1], u10 = u[2], u11 = u[3];
        const int s = 1 << p;
        #pragma unroll
        for (int it = 0; it < 8; ++it) {
            int pp = tid + 512*it;
            int i0 = ((pp >> p) << (p+1)) | (pp & (s-1));
            int i1 = i0 + s;
            float2 a0 = amp[i0], a1 = amp[i1];
            apply_gate(a0, a1, u00, u01, u10, u11);
            amp[i0] = a0; amp[i1] = a1;
        }
        __syncthreads();
    }
    // readout: idx = tid + 512*it -> it bit p2 = idx bit 9+p2 <-> qubit 6-p2
    float2 bv[16];
    #pragma unroll
    for (int it = 0; it < 16; ++it) bv[it] = amp[tid + 512*it];
    #pragma unroll
    for (int p2 = 0; p2 < 4; ++p2) {
        const float2* u = ub + (6 - p2)*4;
        float2 u00 = u[0], u01 = u[1], u10 = u[2], u11 = u[3];
        #pragma unroll
        for (int it = 0; it < 16; ++it)
            if (!(it & (1<<p2)))
                apply_gate(bv[it], bv[it | (1<<p2)], u00, u01, u10, u11);
    }
    const size_t base = (size_t)b*65536 + c*8192;
    #pragma unroll
    for (int it = 0; it < 16; ++it) {
        float2 av = bv[it];
        __half2 hv = __floats2half2_rn(av.x, av.y);
        unsigned int u; __builtin_memcpy(&u, &hv, 4);
        state[base + tid + 512*it] = u;
    }
}

// ---------------- K3: qubits 0..2 + probs -> packed bf16 hi/lo (in place) ----------------
__global__ __launch_bounds__(256) void k_sim2(
        const float2* __restrict__ U1, unsigned int* __restrict__ state) {
    const int b = blockIdx.x >> 3, jc = blockIdx.x & 7;
    const int tid = threadIdx.x;
    const float2* ub = U1 + b*64;
    const float2 g2a = ub[8],  g2b = ub[9],  g2c = ub[10], g2d = ub[11];
    const float2 g1a = ub[4],  g1b = ub[5],  g1c = ub[6],  g1d = ub[7];
    const float2 g0a = ub[0],  g0b = ub[1],  g0c = ub[2],  g0d = ub[3];
    const size_t sb = (size_t)b*65536;
    for (int it = 0; it < 4; ++it) {
        const int j = jc*1024 + tid + 256*it;
        float2 a[8];
        #pragma unroll
        for (int k = 0; k < 8; ++k) {
            unsigned int u = state[sb + j + (k<<13)];
            __half2 hv; __builtin_memcpy(&hv, &u, 4);
            float2 f = __half22float2(hv);
            a[k] = make_float2(f.x, f.y);
        }
        apply_gate(a[0], a[1], g2a, g2b, g2c, g2d);
        apply_gate(a[2], a[3], g2a, g2b, g2c, g2d);
        apply_gate(a[4], a[5], g2a, g2b, g2c, g2d);
        apply_gate(a[6], a[7], g2a, g2b, g2c, g2d);
        apply_gate(a[0], a[2], g1a, g1b, g1c, g1d);
        apply_gate(a[1], a[3], g1a, g1b, g1c, g1d);
        apply_gate(a[4], a[6], g1a, g1b, g1c, g1d);
        apply_gate(a[5], a[7], g1a, g1b, g1c, g1d);
        apply_gate(a[0], a[4], g0a, g0b, g0c, g0d);
        apply_gate(a[1], a[5], g0a, g0b, g0c, g0d);
        apply_gate(a[2], a[6], g0a, g0b, g0c, g0d);
        apply_gate(a[3], a[7], g0a, g0b, g0c, g0d);
        #pragma unroll
        for (int k = 0; k < 8; ++k) {
            float pr = a[k].x*a[k].x + a[k].y*a[k].y;
            unsigned hiu = __float_as_uint(pr) & 0xffff0000u;   // bf16-hi (truncate)
            float lo = pr - __uint_as_float(hiu);
            state[sb + j + (k<<13)] = hiu | f2bf_rn(lo);        // packed (hi<<16)|lo
        }
    }
}

// ---------------- K4: bf16 split MFMA GEMM, split-K ----------------
// C = Ahi*Bhi + Ahi*Blo + Alo*Bhi ; A packed u32 [256][K], B = Wd1 fp32 [K][256]
// block tile 128m x 128n x 512k ; grid (128 ks, 2 nt, 2 mt); 4 waves (2x2), wave 64x64.
__global__ __launch_bounds__(256, 3) void k_gemm(
        const unsigned int* __restrict__ Apk, const float* __restrict__ Wd1,
        float* __restrict__ partial) {
    __shared__ unsigned int lA[128*32];  // [m][k] packed, 8x16B chunks/row, chunk c at c^(m&7)
    __shared__ float lB[32*128];         // [k][n] fp32
    const int ks = blockIdx.x, nt = blockIdx.y, mt = blockIdx.z;
    const int k0 = ks*512, n0 = nt*128, m0 = mt*128;
    const int tid = threadIdx.x, wave = tid >> 6, lane = tid & 63;
    const int mw = wave >> 1, nw = wave & 1;
    const int h = lane >> 5, l32 = lane & 31;
    f32x16 acc[2][2] = {};

    for (int s = 0; s < 16; ++s) {
        const int kb = k0 + s*32;
        // A staging: 16 x 1KB, swizzled global chunk so LDS chunk c' holds global chunk c'^(r&7)
        #pragma unroll
        for (int ai = 0; ai < 4; ++ai) {
            int ia = wave*4 + ai;
            int r = ia*8 + (lane >> 3);
            int cch = (lane & 7) ^ (r & 7);
            gll16(Apk + (size_t)(m0 + r)*KDIM + kb + cch*4, &lA[ia*256]);
        }
        // B staging: 16 x 1KB, straight [k][n]
        #pragma unroll
        for (int bi = 0; bi < 4; ++bi) {
            int ib = wave*4 + bi;
            int kr = ib*2 + h;
            gll16(Wd1 + (size_t)(kb + kr)*256 + n0 + l32*4, &lB[ib*256]);
        }
        __syncthreads();
        #pragma unroll
        for (int kk = 0; kk < 2; ++kk) {
            // B fragments: col-wise reads (conflict-free), convert fp32 -> bf16 hi/lo
            bf16x8 Bh[2], Bl[2];
            #pragma unroll
            for (int j2 = 0; j2 < 2; ++j2) {
                int col = nw*64 + j2*32 + l32;
                int kb2 = kk*16 + h*8;
                float f[8];
                #pragma unroll
                for (int j = 0; j < 8; ++j) f[j] = lB[(kb2 + j)*128 + col];
                int hd[4], ld[4];
                #pragma unroll
                for (int d = 0; d < 4; ++d) {
                    unsigned u0 = __float_as_uint(f[2*d]);
                    unsigned u1 = __float_as_uint(f[2*d+1]);
                    hd[d] = (int)__builtin_amdgcn_perm(u1, u0, 0x07060302u);
                    float l0 = f[2*d]   - __uint_as_float(u0 & 0xffff0000u);
                    float l1 = f[2*d+1] - __uint_as_float(u1 & 0xffff0000u);
                    ld[d] = (int)((f2bf_rn(l1) << 16) | f2bf_rn(l0));
                }
                Bh[j2] = mk_frag(hd[0], hd[1], hd[2], hd[3]);
                Bl[j2] = mk_frag(ld[0], ld[1], ld[2], ld[3]);
            }
            #pragma unroll
            for (int mt2 = 0; mt2 < 2; ++mt2) {
                int R = mw*64 + mt2*32 + l32;
                int ch0 = kk*4 + h*2;
                int sw = R & 7;
                int4 wa = *(const int4*)&lA[R*32 + ((ch0 ^ sw) << 2)];
                int4 wb = *(const int4*)&lA[R*32 + (((ch0+1) ^ sw) << 2)];
                unsigned w0 = (unsigned)wa.x, w1 = (unsigned)wa.y, w2 = (unsigned)wa.z, w3 = (unsigned)wa.w;
                unsigned w4 = (unsigned)wb.x, w5 = (unsigned)wb.y, w6 = (unsigned)wb.z, w7 = (unsigned)wb.w;
                bf16x8 Ah = mk_frag((int)__builtin_amdgcn_perm(w1, w0, 0x07060302u),
                                    (int)__builtin_amdgcn_perm(w3, w2, 0x07060302u),
                                    (int)__builtin_amdgcn_perm(w5, w4, 0x07060302u),
                                    (int)__builtin_amdgcn_perm(w7, w6, 0x07060302u));
                bf16x8 Al = mk_frag((int)__builtin_amdgcn_perm(w1, w0, 0x05040100u),
                                    (int)__builtin_amdgcn_perm(w3, w2, 0x05040100u),
                                    (int)__builtin_amdgcn_perm(w5, w4, 0x05040100u),
                                    (int)__builtin_amdgcn_perm(w7, w6, 0x05040100u));
                #pragma unroll
                for (int j2 = 0; j2 < 2; ++j2) {
                    acc[mt2][j2] = __builtin_amdgcn_mfma_f32_32x32x16_bf16(Ah, Bh[j2], acc[mt2][j2], 0, 0, 0);
                    acc[mt2][j2] = __builtin_amdgcn_mfma_f32_32x32x16_bf16(Ah, Bl[j2], acc[mt2][j2], 0, 0, 0);
                    acc[mt2][j2] = __builtin_amdgcn_mfma_f32_32x32x16_bf16(Al, Bh[j2], acc[mt2][j2], 0, 0, 0);
                }
            }
        }
        __syncthreads();
    }
    // epilogue: C/D layout col=lane&31, row=(reg&3)+8*(reg>>2)+4*(lane>>5)
    float* pp = partial + (size_t)ks*65536;
    #pragma unroll
    for (int mt2 = 0; mt2 < 2; ++mt2) {
        #pragma unroll
        for (int j2 = 0; j2 < 2; ++j2) {
            int n = n0 + nw*64 + j2*32 + l32;
            int mb = m0 + mw*64 + mt2*32 + 4*h;
            #pragma unroll
            for (int q = 0; q < 16; ++q) {
                int m = mb + (q & 3) + 8*(q >> 2);
                pp[m*256 + n] = acc[mt2][j2][q];
            }
        }
    }
}

// ---------------- K5: reduce partials + bias + relu + final GEMV + bias + relu ----
__global__ __launch_bounds__(256) void k_final(
        const float* __restrict__ partial, const float* __restrict__ bd1,
        const float* __restrict__ Wd2, const float* __restrict__ bd2,
        float* __restrict__ out) {
    __shared__ float row[256];
    const int m = blockIdx.x, t = threadIdx.x;
    float acc = 0.f;
    const float* p = partial + (size_t)m*256 + t;
    #pragma unroll 8
    for (int kc = 0; kc < 128; ++kc) acc += p[(size_t)kc*65536];
    row[t] = fmaxf(acc + bd1[t], 0.f);
    __syncthreads();
    if (t < 64) {
        float o = bd2[t];
        #pragma unroll 8
        for (int n = 0; n < 256; ++n) o = fmaf(row[n], Wd2[n*64 + t], o);
        out[m*64 + t] = fmaxf(o, 0.f);
    }
}

extern "C" void kernel_launch(void* const* d_in, const int* in_sizes, int n_in,
                              void* d_out, int out_size, void* d_ws, size_t ws_size,
                              hipStream_t stream) {
    const float* x       = (const float*)d_in[0];
    const float* W1      = (const float*)d_in[1];
    const float* b1      = (const float*)d_in[2];
    const float* W2      = (const float*)d_in[3];
    const float* b2      = (const float*)d_in[4];
    const float* scaling = (const float*)d_in[5];
    const float* Wd1     = (const float*)d_in[6];
    const float* bd1     = (const float*)d_in[7];
    const float* Wd2     = (const float*)d_in[8];
    const float* bd2     = (const float*)d_in[9];
    float* out = (float*)d_out;

    char* ws = (char*)d_ws;
    float2* v0 = (float2*)(ws + 0);                        //  64 KB
    float2* U1 = (float2*)(ws + 65536);                    // 128 KB
    unsigned int* state = (unsigned int*)(ws + (1u<<20));  //  64 MB: half2 -> packed bf16 probs
    float* partial = (float*)(ws + (1u<<20) + (size_t)64*1024*1024); // 32 MB

    hipLaunchKernelGGL(k_encoder, dim3(256), dim3(128), 0, stream,
                       x, W1, b1, W2, b2, scaling, v0, U1);
    hipLaunchKernelGGL(k_sim1, dim3(2048), dim3(512), 0, stream, v0, U1, state);
    hipLaunchKernelGGL(k_sim2, dim3(2048), dim3(256), 0, stream, U1, state);
    hipLaunchKernelGGL(k_gemm, dim3(128, 2, 2), dim3(256), 0, stream,
                       state, Wd1, partial);
    hipLaunchKernelGGL(k_final, dim3(256), dim3(256), 0, stream,
                       partial, bd1, Wd2, bd2, out);
}

// Round 3
// 271.823 us; speedup vs baseline: 1.7132x; 1.0152x over previous
//
#include <hip/hip_runtime.h>
#include <hip/hip_fp16.h>

#define PI_F 3.14159265358979323846f
#define KDIM 65536

typedef __attribute__((ext_vector_type(8))) __bf16 bf16x8;
typedef __attribute__((ext_vector_type(16))) float f32x16;

__device__ __forceinline__ float2 cmul(float2 a, float2 b) {
    return make_float2(a.x*b.x - a.y*b.y, a.x*b.y + a.y*b.x);
}

__device__ __forceinline__ void apply_gate(float2& a0, float2& a1,
                                           float2 u00, float2 u01, float2 u10, float2 u11) {
    float2 n0 = make_float2(
        u00.x*a0.x - u00.y*a0.y + u01.x*a1.x - u01.y*a1.y,
        u00.x*a0.y + u00.y*a0.x + u01.x*a1.y + u01.y*a1.x);
    float2 n1 = make_float2(
        u10.x*a0.x - u10.y*a0.y + u11.x*a1.x - u11.y*a1.y,
        u10.x*a0.y + u10.y*a0.x + u11.x*a1.y + u11.y*a1.x);
    a0 = n0; a1 = n1;
}

__device__ __forceinline__ unsigned f2bf_rn(float x) {
    unsigned u = __float_as_uint(x);
    return (u + 0x7fffu + ((u >> 16) & 1u)) >> 16;
}

union FragU { int4 i4; bf16x8 v; };
__device__ __forceinline__ bf16x8 mk_frag(int a, int b, int c, int d) {
    FragU u; u.i4 = make_int4(a, b, c, d); return u.v;
}

// async global->LDS, 16B per lane; LDS dest is wave-uniform base + lane*16
__device__ __forceinline__ void gll16(const void* g, void* l) {
    __builtin_amdgcn_global_load_lds(
        (const __attribute__((address_space(1))) void*)g,
        (__attribute__((address_space(3))) void*)l, 16, 0, 0);
}

// ---------------- K1: encoder MLP -> U3 matrices ----------------
__global__ __launch_bounds__(128) void k_encoder(
        const float* __restrict__ x, const float* __restrict__ W1,
        const float* __restrict__ b1, const float* __restrict__ W2,
        const float* __restrict__ b2, const float* __restrict__ scaling,
        float2* __restrict__ v0, float2* __restrict__ U1) {
    __shared__ float xr[64];
    __shared__ float h[128];
    __shared__ float ang[96];
    const int b = blockIdx.x, t = threadIdx.x;
    if (t < 64) xr[t] = x[b*64 + t];
    __syncthreads();
    {
        float acc = b1[t];
        #pragma unroll 8
        for (int f = 0; f < 64; ++f) acc = fmaf(xr[f], W1[f*128 + t], acc);
        h[t] = fmaxf(acc, 0.f);
    }
    __syncthreads();
    if (t < 96) {
        float acc = b2[t];
        #pragma unroll 8
        for (int f = 0; f < 128; ++f) acc = fmaf(h[f], W2[f*96 + t], acc);
        int q = (t/3) & 15;
        ang[t] = tanhf(acc) * scaling[q] * PI_F;
    }
    __syncthreads();
    if (t < 32) {
        int l = t >> 4, q = t & 15;
        const float* a = ang + l*48 + q*3;
        float st, ct, sp, cp, sl, cl;
        sincosf(a[0]*0.5f, &st, &ct);
        sincosf(a[1]*0.5f, &sp, &cp);
        sincosf(a[2]*0.5f, &sl, &cl);
        float2 A00 = make_float2( cp*ct,  sp*st);
        float2 A01 = make_float2(-sp*ct, -cp*st);
        float2 A10 = make_float2( sp*ct, -cp*st);
        float2 A11 = make_float2( cp*ct, -sp*st);
        float2 e0 = make_float2(cl, -sl), e1 = make_float2(cl, sl);
        if (l == 0) {
            float2* v = v0 + (b*16 + q)*2;
            v[0] = cmul(e0, A00);
            v[1] = cmul(e1, A10);
        } else {
            float2* u = U1 + (b*16 + q)*4;
            u[0] = cmul(e0, A00); u[1] = cmul(e0, A01);
            u[2] = cmul(e1, A10); u[3] = cmul(e1, A11);
        }
    }
}

// ---------------- K2: product state + layer1 gates on qubits 15..4 ----------------
// Block = (b, c of 16 chunks): 4096 amps in LDS (padded). 3 register phases:
// bits 0-3 (q15-12), bits 4-7 (q11-8), bits 8-11 (q7-4). 2 barriers total.
// pad: phys(idx) = idx + (idx>>4) + (idx>>8) -> every phase is exactly
// 4 lanes/bank-pair for b64 accesses (the conflict-free minimum).
__global__ __launch_bounds__(256) void k_sim1(
        const float2* __restrict__ v0, const float2* __restrict__ U1,
        unsigned int* __restrict__ state) {
    __shared__ float2 amp[4368];   // 4095+255+15 max phys
    const int b = blockIdx.x >> 4, c = blockIdx.x & 15;
    const int t = threadIdx.x;
    const float2* v = v0 + b*32;
    const float2* ub = U1 + b*64;
    // init: z = (c<<12) | (t<<4) | i ; w_p = z_p^z_{p+1} (p<=13),
    // w14 = z14^z15^z0, w15 = z15^z0 ; qubit q <-> bit 15-q
    const int zbase = (c << 12) | (t << 4);
    const int zz = zbase ^ (zbase >> 1);
    float2 F = make_float2(1.f, 0.f);
    #pragma unroll
    for (int p = 4; p <= 11; ++p)
        F = cmul(F, v[(15-p)*2 + ((zz>>p)&1)]);
    F = cmul(F, v[6 + ((c ^ (c>>1)) & 1)]);          // p=12: c0^c1
    F = cmul(F, v[4 + (((c>>1) ^ (c>>2)) & 1)]);     // p=13: c1^c2
    const int c2 = (c>>2)&1, c3 = (c>>3)&1;
    float2 H0 = cmul(cmul(F, v[2 + (c2^c3)]),   v[c3]);      // z0 = 0
    float2 H1 = cmul(cmul(F, v[2 + (c2^c3^1)]), v[c3^1]);    // z0 = 1
    const int t4 = t & 1;  // z bit 4
    float2 a[16];
    #pragma unroll
    for (int i = 0; i < 16; ++i) {
        int i0 = i&1, i1 = (i>>1)&1, i2 = (i>>2)&1, i3 = i>>3;
        float2 lo = cmul(cmul(v[30 + (i0^i1)], v[28 + (i1^i2)]),
                         cmul(v[26 + (i2^i3)], v[24 + (i3^t4)]));
        a[i] = cmul(lo, i0 ? H1 : H0);
    }
    // phase1 gates: idx bit p <-> qubit 15-p, p = 0..3
    #pragma unroll
    for (int p = 0; p < 4; ++p) {
        const float2* u = ub + (15-p)*4;
        float2 u00 = u[0], u01 = u[1], u10 = u[2], u11 = u[3];
        #pragma unroll
        for (int i = 0; i < 16; ++i)
            if (!(i & (1<<p)))
                apply_gate(a[i], a[i | (1<<p)], u00, u01, u10, u11);
    }
    {
        const int ph1 = 17*t + (t>>4);
        #pragma unroll
        for (int i = 0; i < 16; ++i) amp[ph1 + i] = a[i];
    }
    __syncthreads();
    // phase2: idx = (t&15) | (j<<4) | ((t>>4)<<8) -> bits 4-7 in regs (qubits 11-8)
    {
        const int ph2 = (t & 15) + 273*(t >> 4);
        #pragma unroll
        for (int j = 0; j < 16; ++j) a[j] = amp[ph2 + 17*j];
        #pragma unroll
        for (int p = 0; p < 4; ++p) {
            const float2* u = ub + (11-p)*4;
            float2 u00 = u[0], u01 = u[1], u10 = u[2], u11 = u[3];
            #pragma unroll
            for (int j = 0; j < 16; ++j)
                if (!(j & (1<<p)))
                    apply_gate(a[j], a[j | (1<<p)], u00, u01, u10, u11);
        }
        #pragma unroll
        for (int j = 0; j < 16; ++j) amp[ph2 + 17*j] = a[j];
    }
    __syncthreads();
    // phase3: idx = t | (j<<8) -> bits 8-11 in regs (qubits 7-4), then global write
    {
        const int ph3 = t + (t >> 4);
        #pragma unroll
        for (int j = 0; j < 16; ++j) a[j] = amp[ph3 + 273*j];
        #pragma unroll
        for (int p = 0; p < 4; ++p) {
            const float2* u = ub + (7-p)*4;
            float2 u00 = u[0], u01 = u[1], u10 = u[2], u11 = u[3];
            #pragma unroll
            for (int j = 0; j < 16; ++j)
                if (!(j & (1<<p)))
                    apply_gate(a[j], a[j | (1<<p)], u00, u01, u10, u11);
        }
        const size_t base = (size_t)b*65536 + (c << 12) + t;
        #pragma unroll
        for (int j = 0; j < 16; ++j) {
            __half2 hv = __floats2half2_rn(a[j].x, a[j].y);
            unsigned int u; __builtin_memcpy(&u, &hv, 4);
            state[base + (j << 8)] = u;
        }
    }
}

// ---------------- K3: qubits 3..0 (bits 12-15) + probs -> packed bf16 hi/lo ----------------
__global__ __launch_bounds__(256) void k_sim2(
        const float2* __restrict__ U1, unsigned int* __restrict__ state) {
    const int b = blockIdx.x >> 4, jc = blockIdx.x & 15;
    const int tid = threadIdx.x;
    const int j = jc*256 + tid;
    const float2* ub = U1 + b*64;
    const size_t sb = (size_t)b*65536;
    float2 a[16];
    #pragma unroll
    for (int s = 0; s < 16; ++s) {
        unsigned int u = state[sb + (s << 12) + j];
        __half2 hv; __builtin_memcpy(&hv, &u, 4);
        float2 f = __half22float2(hv);
        a[s] = make_float2(f.x, f.y);
    }
    // s bit ss = z bit 12+ss <-> qubit 3-ss
    #pragma unroll
    for (int ss = 0; ss < 4; ++ss) {
        const float2* u = ub + (3-ss)*4;
        float2 u00 = u[0], u01 = u[1], u10 = u[2], u11 = u[3];
        #pragma unroll
        for (int s = 0; s < 16; ++s)
            if (!(s & (1<<ss)))
                apply_gate(a[s], a[s | (1<<ss)], u00, u01, u10, u11);
    }
    #pragma unroll
    for (int s = 0; s < 16; ++s) {
        float pr = a[s].x*a[s].x + a[s].y*a[s].y;
        unsigned hiu = __float_as_uint(pr) & 0xffff0000u;   // bf16-hi (truncate)
        float lo = pr - __uint_as_float(hiu);
        state[sb + (s << 12) + j] = hiu | f2bf_rn(lo);      // packed (hi<<16)|lo
    }
}

// ---------------- K4: bf16 split MFMA GEMM, split-K ----------------
// C = Ahi*Bhi + Ahi*Blo + Alo*Bhi ; A packed u32 [256][K], B = Wd1 fp32 [K][256]
// block tile 128m x 128n x 512k ; grid (128 ks, 2 nt, 2 mt); 4 waves (2x2), wave 64x64.
__global__ __launch_bounds__(256, 3) void k_gemm(
        const unsigned int* __restrict__ Apk, const float* __restrict__ Wd1,
        float* __restrict__ partial) {
    __shared__ unsigned int lA[128*32];  // [m][k] packed, 8x16B chunks/row, chunk c at c^(m&7)
    __shared__ float lB[32*128];         // [k][n] fp32
    const int ks = blockIdx.x, nt = blockIdx.y, mt = blockIdx.z;
    const int k0 = ks*512, n0 = nt*128, m0 = mt*128;
    const int tid = threadIdx.x, wave = tid >> 6, lane = tid & 63;
    const int mw = wave >> 1, nw = wave & 1;
    const int h = lane >> 5, l32 = lane & 31;
    f32x16 acc[2][2] = {};

    for (int s = 0; s < 16; ++s) {
        const int kb = k0 + s*32;
        // A staging: 16 x 1KB, swizzled global chunk so LDS chunk c' holds global chunk c'^(r&7)
        #pragma unroll
        for (int ai = 0; ai < 4; ++ai) {
            int ia = wave*4 + ai;
            int r = ia*8 + (lane >> 3);
            int cch = (lane & 7) ^ (r & 7);
            gll16(Apk + (size_t)(m0 + r)*KDIM + kb + cch*4, &lA[ia*256]);
        }
        // B staging: 16 x 1KB, straight [k][n]
        #pragma unroll
        for (int bi = 0; bi < 4; ++bi) {
            int ib = wave*4 + bi;
            int kr = ib*2 + h;
            gll16(Wd1 + (size_t)(kb + kr)*256 + n0 + l32*4, &lB[ib*256]);
        }
        __syncthreads();
        #pragma unroll
        for (int kk = 0; kk < 2; ++kk) {
            // B fragments: col-wise reads (conflict-free), convert fp32 -> bf16 hi/lo
            bf16x8 Bh[2], Bl[2];
            #pragma unroll
            for (int j2 = 0; j2 < 2; ++j2) {
                int col = nw*64 + j2*32 + l32;
                int kb2 = kk*16 + h*8;
                float f[8];
                #pragma unroll
                for (int j = 0; j < 8; ++j) f[j] = lB[(kb2 + j)*128 + col];
                int hd[4], ld[4];
                #pragma unroll
                for (int d = 0; d < 4; ++d) {
                    unsigned u0 = __float_as_uint(f[2*d]);
                    unsigned u1 = __float_as_uint(f[2*d+1]);
                    hd[d] = (int)__builtin_amdgcn_perm(u1, u0, 0x07060302u);
                    float l0 = f[2*d]   - __uint_as_float(u0 & 0xffff0000u);
                    float l1 = f[2*d+1] - __uint_as_float(u1 & 0xffff0000u);
                    ld[d] = (int)((f2bf_rn(l1) << 16) | f2bf_rn(l0));
                }
                Bh[j2] = mk_frag(hd[0], hd[1], hd[2], hd[3]);
                Bl[j2] = mk_frag(ld[0], ld[1], ld[2], ld[3]);
            }
            #pragma unroll
            for (int mt2 = 0; mt2 < 2; ++mt2) {
                int R = mw*64 + mt2*32 + l32;
                int ch0 = kk*4 + h*2;
                int sw = R & 7;
                int4 wa = *(const int4*)&lA[R*32 + ((ch0 ^ sw) << 2)];
                int4 wb = *(const int4*)&lA[R*32 + (((ch0+1) ^ sw) << 2)];
                unsigned w0 = (unsigned)wa.x, w1 = (unsigned)wa.y, w2 = (unsigned)wa.z, w3 = (unsigned)wa.w;
                unsigned w4 = (unsigned)wb.x, w5 = (unsigned)wb.y, w6 = (unsigned)wb.z, w7 = (unsigned)wb.w;
                bf16x8 Ah = mk_frag((int)__builtin_amdgcn_perm(w1, w0, 0x07060302u),
                                    (int)__builtin_amdgcn_perm(w3, w2, 0x07060302u),
                                    (int)__builtin_amdgcn_perm(w5, w4, 0x07060302u),
                                    (int)__builtin_amdgcn_perm(w7, w6, 0x07060302u));
                bf16x8 Al = mk_frag((int)__builtin_amdgcn_perm(w1, w0, 0x05040100u),
                                    (int)__builtin_amdgcn_perm(w3, w2, 0x05040100u),
                                    (int)__builtin_amdgcn_perm(w5, w4, 0x05040100u),
                                    (int)__builtin_amdgcn_perm(w7, w6, 0x05040100u));
                #pragma unroll
                for (int j2 = 0; j2 < 2; ++j2) {
                    acc[mt2][j2] = __builtin_amdgcn_mfma_f32_32x32x16_bf16(Ah, Bh[j2], acc[mt2][j2], 0, 0, 0);
                    acc[mt2][j2] = __builtin_amdgcn_mfma_f32_32x32x16_bf16(Ah, Bl[j2], acc[mt2][j2], 0, 0, 0);
                    acc[mt2][j2] = __builtin_amdgcn_mfma_f32_32x32x16_bf16(Al, Bh[j2], acc[mt2][j2], 0, 0, 0);
                }
            }
        }
        __syncthreads();
    }
    // epilogue: C/D layout col=lane&31, row=(reg&3)+8*(reg>>2)+4*(lane>>5)
    float* pp = partial + (size_t)ks*65536;
    #pragma unroll
    for (int mt2 = 0; mt2 < 2; ++mt2) {
        #pragma unroll
        for (int j2 = 0; j2 < 2; ++j2) {
            int n = n0 + nw*64 + j2*32 + l32;
            int mb = m0 + mw*64 + mt2*32 + 4*h;
            #pragma unroll
            for (int q = 0; q < 16; ++q) {
                int m = mb + (q & 3) + 8*(q >> 2);
                pp[m*256 + n] = acc[mt2][j2][q];
            }
        }
    }
}

// ---------------- K5: reduce partials + bias + relu + final GEMV + bias + relu ----
__global__ __launch_bounds__(256) void k_final(
        const float* __restrict__ partial, const float* __restrict__ bd1,
        const float* __restrict__ Wd2, const float* __restrict__ bd2,
        float* __restrict__ out) {
    __shared__ float row[256];
    const int m = blockIdx.x, t = threadIdx.x;
    float acc = 0.f;
    const float* p = partial + (size_t)m*256 + t;
    #pragma unroll 8
    for (int kc = 0; kc < 128; ++kc) acc += p[(size_t)kc*65536];
    row[t] = fmaxf(acc + bd1[t], 0.f);
    __syncthreads();
    if (t < 64) {
        float o = bd2[t];
        #pragma unroll 8
        for (int n = 0; n < 256; ++n) o = fmaf(row[n], Wd2[n*64 + t], o);
        out[m*64 + t] = fmaxf(o, 0.f);
    }
}

extern "C" void kernel_launch(void* const* d_in, const int* in_sizes, int n_in,
                              void* d_out, int out_size, void* d_ws, size_t ws_size,
                              hipStream_t stream) {
    const float* x       = (const float*)d_in[0];
    const float* W1      = (const float*)d_in[1];
    const float* b1      = (const float*)d_in[2];
    const float* W2      = (const float*)d_in[3];
    const float* b2      = (const float*)d_in[4];
    const float* scaling = (const float*)d_in[5];
    const float* Wd1     = (const float*)d_in[6];
    const float* bd1     = (const float*)d_in[7];
    const float* Wd2     = (const float*)d_in[8];
    const float* bd2     = (const float*)d_in[9];
    float* out = (float*)d_out;

    char* ws = (char*)d_ws;
    float2* v0 = (float2*)(ws + 0);                        //  64 KB
    float2* U1 = (float2*)(ws + 65536);                    // 128 KB
    unsigned int* state = (unsigned int*)(ws + (1u<<20));  //  64 MB: half2 -> packed bf16 probs
    float* partial = (float*)(ws + (1u<<20) + (size_t)64*1024*1024); // 32 MB

    hipLaunchKernelGGL(k_encoder, dim3(256), dim3(128), 0, stream,
                       x, W1, b1, W2, b2, scaling, v0, U1);
    hipLaunchKernelGGL(k_sim1, dim3(4096), dim3(256), 0, stream, v0, U1, state);
    hipLaunchKernelGGL(k_sim2, dim3(4096), dim3(256), 0, stream, U1, state);
    hipLaunchKernelGGL(k_gemm, dim3(128, 2, 2), dim3(256), 0, stream,
                       state, Wd1, partial);
    hipLaunchKernelGGL(k_final, dim3(256), dim3(256), 0, stream,
                       partial, bd1, Wd2, bd2, out);
}

// Round 4
// 238.766 us; speedup vs baseline: 1.9504x; 1.1385x over previous
//
#include <hip/hip_runtime.h>
#include <hip/hip_fp16.h>

#define PI_F 3.14159265358979323846f
#define KDIM 65536

typedef __attribute__((ext_vector_type(8))) __bf16 bf16x8;
typedef __attribute__((ext_vector_type(16))) float f32x16;
typedef __attribute__((ext_vector_type(2))) float v2f;

// ---------- packed-fp32 complex helpers (target: v_pk_fma_f32) ----------
__device__ __forceinline__ v2f pfma(v2f a, v2f b, v2f c) {
    return __builtin_elementwise_fma(a, b, c);
}
__device__ __forceinline__ v2f vswap(v2f a) { return __builtin_shufflevector(a, a, 1, 0); }
__device__ __forceinline__ v2f vsplat(float x) { v2f r; r.x = x; r.y = x; return r; }
__device__ __forceinline__ v2f mkc(v2f u) { v2f r; r.x = -u.y; r.y = u.y; return r; }
// complex mul: a*b = splat(a.re)*b + {-a.im,a.im}*swap(b)
__device__ __forceinline__ v2f cmul(v2f a, v2f b) {
    return pfma(mkc(a), vswap(b), vsplat(a.x) * b);
}
// one gate on an amplitude pair: 8 packed ops
__device__ __forceinline__ void gate_pk(v2f& a0, v2f& a1,
        float x00, float x01, float x10, float x11,
        v2f c00, v2f c01, v2f c10, v2f c11) {
    v2f a0s = vswap(a0), a1s = vswap(a1);
    v2f n0 = vsplat(x00) * a0;
    n0 = pfma(c00, a0s, n0);
    n0 = pfma(vsplat(x01), a1, n0);
    n0 = pfma(c01, a1s, n0);
    v2f n1 = vsplat(x10) * a0;
    n1 = pfma(c10, a0s, n1);
    n1 = pfma(vsplat(x11), a1, n1);
    n1 = pfma(c11, a1s, n1);
    a0 = n0; a1 = n1;
}

__device__ __forceinline__ unsigned f2bf_rn(float x) {
    unsigned u = __float_as_uint(x);
    return (u + 0x7fffu + ((u >> 16) & 1u)) >> 16;
}

union FragU { int4 i4; bf16x8 v; };
__device__ __forceinline__ bf16x8 mk_frag(int a, int b, int c, int d) {
    FragU u; u.i4 = make_int4(a, b, c, d); return u.v;
}

// async global->LDS, 16B per lane; LDS dest is wave-uniform base + lane*16
__device__ __forceinline__ void gll16(const void* g, void* l) {
    __builtin_amdgcn_global_load_lds(
        (const __attribute__((address_space(1))) void*)g,
        (__attribute__((address_space(3))) void*)l, 16, 0, 0);
}

// ---------------- K1: encoder MLP -> U3 matrices ----------------
__global__ __launch_bounds__(128) void k_encoder(
        const float* __restrict__ x, const float* __restrict__ W1,
        const float* __restrict__ b1, const float* __restrict__ W2,
        const float* __restrict__ b2, const float* __restrict__ scaling,
        float2* __restrict__ v0, float2* __restrict__ U1) {
    __shared__ float xr[64];
    __shared__ float h[128];
    __shared__ float ang[96];
    const int b = blockIdx.x, t = threadIdx.x;
    if (t < 64) xr[t] = x[b*64 + t];
    __syncthreads();
    {
        float acc = b1[t];
        #pragma unroll 8
        for (int f = 0; f < 64; ++f) acc = fmaf(xr[f], W1[f*128 + t], acc);
        h[t] = fmaxf(acc, 0.f);
    }
    __syncthreads();
    if (t < 96) {
        float acc = b2[t];
        #pragma unroll 8
        for (int f = 0; f < 128; ++f) acc = fmaf(h[f], W2[f*96 + t], acc);
        int q = (t/3) & 15;
        ang[t] = tanhf(acc) * scaling[q] * PI_F;
    }
    __syncthreads();
    if (t < 32) {
        int l = t >> 4, q = t & 15;
        const float* a = ang + l*48 + q*3;
        float st, ct, sp, cp, sl, cl;
        sincosf(a[0]*0.5f, &st, &ct);
        sincosf(a[1]*0.5f, &sp, &cp);
        sincosf(a[2]*0.5f, &sl, &cl);
        float2 A00 = make_float2( cp*ct,  sp*st);
        float2 A01 = make_float2(-sp*ct, -cp*st);
        float2 A10 = make_float2( sp*ct, -cp*st);
        float2 A11 = make_float2( cp*ct, -sp*st);
        float2 e0 = make_float2(cl, -sl), e1 = make_float2(cl, sl);
        float2 r00 = make_float2(e0.x*A00.x - e0.y*A00.y, e0.x*A00.y + e0.y*A00.x);
        float2 r01 = make_float2(e0.x*A01.x - e0.y*A01.y, e0.x*A01.y + e0.y*A01.x);
        float2 r10 = make_float2(e1.x*A10.x - e1.y*A10.y, e1.x*A10.y + e1.y*A10.x);
        float2 r11 = make_float2(e1.x*A11.x - e1.y*A11.y, e1.x*A11.y + e1.y*A11.x);
        if (l == 0) {
            float2* v = v0 + (b*16 + q)*2;
            v[0] = r00;
            v[1] = r10;
        } else {
            float2* u = U1 + (b*16 + q)*4;
            u[0] = r00; u[1] = r01;
            u[2] = r10; u[3] = r11;
        }
    }
}

// ---------------- K2: product state + layer1 gates on qubits 15..4 ----------------
// Block = (b, c of 16 chunks): 4096 amps in LDS (padded). 3 register phases:
// bits 0-3 (q15-12), bits 4-7 (q11-8), bits 8-11 (q7-4). 2 barriers total.
// pad: phys(idx) = idx + (idx>>4) + (idx>>8) -> conflict-free minimum for b64.
__global__ __launch_bounds__(256) void k_sim1(
        const float2* __restrict__ v0, const float2* __restrict__ U1,
        unsigned int* __restrict__ state) {
    __shared__ v2f amp[4368];
    const int b = blockIdx.x >> 4, c = blockIdx.x & 15;
    const int t = threadIdx.x;
    const v2f* v = (const v2f*)(v0 + b*32);
    const v2f* ub = (const v2f*)(U1 + b*64);
    // init: z = (c<<12) | (t<<4) | i ; w_p = z_p^z_{p+1} (p<=13),
    // w14 = z14^z15^z0, w15 = z15^z0 ; qubit q <-> bit 15-q
    const int zbase = (c << 12) | (t << 4);
    const int zz = zbase ^ (zbase >> 1);
    v2f F; F.x = 1.f; F.y = 0.f;
    #pragma unroll
    for (int p = 4; p <= 11; ++p)
        F = cmul(F, v[(15-p)*2 + ((zz>>p)&1)]);
    F = cmul(F, v[6 + ((c ^ (c>>1)) & 1)]);          // p=12: c0^c1
    F = cmul(F, v[4 + (((c>>1) ^ (c>>2)) & 1)]);     // p=13: c1^c2
    const int c2 = (c>>2)&1, c3 = (c>>3)&1;
    v2f H0 = cmul(cmul(F, v[2 + (c2^c3)]),   v[c3]);      // z0 = 0
    v2f H1 = cmul(cmul(F, v[2 + (c2^c3^1)]), v[c3^1]);    // z0 = 1
    const int t4 = t & 1;  // z bit 4
    v2f a[16];
    #pragma unroll
    for (int i = 0; i < 16; ++i) {
        int i0 = i&1, i1 = (i>>1)&1, i2 = (i>>2)&1, i3 = i>>3;
        v2f lo = cmul(cmul(v[30 + (i0^i1)], v[28 + (i1^i2)]),
                      cmul(v[26 + (i2^i3)], v[24 + (i3^t4)]));
        a[i] = cmul(lo, i0 ? H1 : H0);
    }
    // phase1 gates: idx bit p <-> qubit 15-p, p = 0..3
    #pragma unroll
    for (int p = 0; p < 4; ++p) {
        const v2f u00 = ub[(15-p)*4+0], u01 = ub[(15-p)*4+1];
        const v2f u10 = ub[(15-p)*4+2], u11 = ub[(15-p)*4+3];
        const v2f c00 = mkc(u00), c01 = mkc(u01), c10 = mkc(u10), c11 = mkc(u11);
        #pragma unroll
        for (int i = 0; i < 16; ++i)
            if (!(i & (1<<p)))
                gate_pk(a[i], a[i | (1<<p)], u00.x, u01.x, u10.x, u11.x, c00, c01, c10, c11);
    }
    {
        const int ph1 = 17*t + (t>>4);
        #pragma unroll
        for (int i = 0; i < 16; ++i) amp[ph1 + i] = a[i];
    }
    __syncthreads();
    // phase2: idx = (t&15) | (j<<4) | ((t>>4)<<8) -> bits 4-7 in regs (qubits 11-8)
    {
        const int ph2 = (t & 15) + 273*(t >> 4);
        #pragma unroll
        for (int j = 0; j < 16; ++j) a[j] = amp[ph2 + 17*j];
        #pragma unroll
        for (int p = 0; p < 4; ++p) {
            const v2f u00 = ub[(11-p)*4+0], u01 = ub[(11-p)*4+1];
            const v2f u10 = ub[(11-p)*4+2], u11 = ub[(11-p)*4+3];
            const v2f c00 = mkc(u00), c01 = mkc(u01), c10 = mkc(u10), c11 = mkc(u11);
            #pragma unroll
            for (int j = 0; j < 16; ++j)
                if (!(j & (1<<p)))
                    gate_pk(a[j], a[j | (1<<p)], u00.x, u01.x, u10.x, u11.x, c00, c01, c10, c11);
        }
        #pragma unroll
        for (int j = 0; j < 16; ++j) amp[ph2 + 17*j] = a[j];
    }
    __syncthreads();
    // phase3: idx = t | (j<<8) -> bits 8-11 in regs (qubits 7-4), then global write
    {
        const int ph3 = t + (t >> 4);
        #pragma unroll
        for (int j = 0; j < 16; ++j) a[j] = amp[ph3 + 273*j];
        #pragma unroll
        for (int p = 0; p < 4; ++p) {
            const v2f u00 = ub[(7-p)*4+0], u01 = ub[(7-p)*4+1];
            const v2f u10 = ub[(7-p)*4+2], u11 = ub[(7-p)*4+3];
            const v2f c00 = mkc(u00), c01 = mkc(u01), c10 = mkc(u10), c11 = mkc(u11);
            #pragma unroll
            for (int j = 0; j < 16; ++j)
                if (!(j & (1<<p)))
                    gate_pk(a[j], a[j | (1<<p)], u00.x, u01.x, u10.x, u11.x, c00, c01, c10, c11);
        }
        const size_t base = (size_t)b*65536 + (c << 12) + t;
        #pragma unroll
        for (int j = 0; j < 16; ++j) {
            __half2 hv = __floats2half2_rn(a[j].x, a[j].y);
            unsigned int u; __builtin_memcpy(&u, &hv, 4);
            state[base + (j << 8)] = u;
        }
    }
}

// ---------------- K3: qubits 3..0 (bits 12-15) + probs -> packed bf16 hi/lo ----------------
__global__ __launch_bounds__(256) void k_sim2(
        const float2* __restrict__ U1, unsigned int* __restrict__ state) {
    const int b = blockIdx.x >> 4, jc = blockIdx.x & 15;
    const int tid = threadIdx.x;
    const int j = jc*256 + tid;
    const v2f* ub = (const v2f*)(U1 + b*64);
    const size_t sb = (size_t)b*65536;
    v2f a[16];
    #pragma unroll
    for (int s = 0; s < 16; ++s) {
        unsigned int u = state[sb + (s << 12) + j];
        __half2 hv; __builtin_memcpy(&hv, &u, 4);
        float2 f = __half22float2(hv);
        a[s].x = f.x; a[s].y = f.y;
    }
    // s bit ss = z bit 12+ss <-> qubit 3-ss
    #pragma unroll
    for (int ss = 0; ss < 4; ++ss) {
        const v2f u00 = ub[(3-ss)*4+0], u01 = ub[(3-ss)*4+1];
        const v2f u10 = ub[(3-ss)*4+2], u11 = ub[(3-ss)*4+3];
        const v2f c00 = mkc(u00), c01 = mkc(u01), c10 = mkc(u10), c11 = mkc(u11);
        #pragma unroll
        for (int s = 0; s < 16; ++s)
            if (!(s & (1<<ss)))
                gate_pk(a[s], a[s | (1<<ss)], u00.x, u01.x, u10.x, u11.x, c00, c01, c10, c11);
    }
    #pragma unroll
    for (int s = 0; s < 16; ++s) {
        float pr = fmaf(a[s].x, a[s].x, a[s].y * a[s].y);
        unsigned hiu = __float_as_uint(pr) & 0xffff0000u;   // bf16-hi (truncate)
        float lo = pr - __uint_as_float(hiu);
        state[sb + (s << 12) + j] = hiu | f2bf_rn(lo);      // packed (hi<<16)|lo
    }
}

// ---------------- K4: bf16 split MFMA GEMM, split-K ----------------
// C = Ahi*Bhi + Ahi*Blo + Alo*Bhi ; A packed u32 [256][K], B = Wd1 fp32 [K][256]
// block tile 128m x 128n x 512k ; grid (128 ks, 2 nt, 2 mt); 4 waves (2x2), wave 64x64.
__global__ __launch_bounds__(256, 3) void k_gemm(
        const unsigned int* __restrict__ Apk, const float* __restrict__ Wd1,
        float* __restrict__ partial) {
    __shared__ unsigned int lA[128*32];  // [m][k] packed, 8x16B chunks/row, chunk c at c^(m&7)
    __shared__ float lB[32*128];         // [k][n] fp32
    const int ks = blockIdx.x, nt = blockIdx.y, mt = blockIdx.z;
    const int k0 = ks*512, n0 = nt*128, m0 = mt*128;
    const int tid = threadIdx.x, wave = tid >> 6, lane = tid & 63;
    const int mw = wave >> 1, nw = wave & 1;
    const int h = lane >> 5, l32 = lane & 31;
    f32x16 acc[2][2] = {};

    for (int s = 0; s < 16; ++s) {
        const int kb = k0 + s*32;
        #pragma unroll
        for (int ai = 0; ai < 4; ++ai) {
            int ia = wave*4 + ai;
            int r = ia*8 + (lane >> 3);
            int cch = (lane & 7) ^ (r & 7);
            gll16(Apk + (size_t)(m0 + r)*KDIM + kb + cch*4, &lA[ia*256]);
        }
        #pragma unroll
        for (int bi = 0; bi < 4; ++bi) {
            int ib = wave*4 + bi;
            int kr = ib*2 + h;
            gll16(Wd1 + (size_t)(kb + kr)*256 + n0 + l32*4, &lB[ib*256]);
        }
        __syncthreads();
        #pragma unroll
        for (int kk = 0; kk < 2; ++kk) {
            bf16x8 Bh[2], Bl[2];
            #pragma unroll
            for (int j2 = 0; j2 < 2; ++j2) {
                int col = nw*64 + j2*32 + l32;
                int kb2 = kk*16 + h*8;
                float f[8];
                #pragma unroll
                for (int j = 0; j < 8; ++j) f[j] = lB[(kb2 + j)*128 + col];
                int hd[4], ld[4];
                #pragma unroll
                for (int d = 0; d < 4; ++d) {
                    unsigned u0 = __float_as_uint(f[2*d]);
                    unsigned u1 = __float_as_uint(f[2*d+1]);
                    hd[d] = (int)__builtin_amdgcn_perm(u1, u0, 0x07060302u);
                    float l0 = f[2*d]   - __uint_as_float(u0 & 0xffff0000u);
                    float l1 = f[2*d+1] - __uint_as_float(u1 & 0xffff0000u);
                    ld[d] = (int)((f2bf_rn(l1) << 16) | f2bf_rn(l0));
                }
                Bh[j2] = mk_frag(hd[0], hd[1], hd[2], hd[3]);
                Bl[j2] = mk_frag(ld[0], ld[1], ld[2], ld[3]);
            }
            #pragma unroll
            for (int mt2 = 0; mt2 < 2; ++mt2) {
                int R = mw*64 + mt2*32 + l32;
                int ch0 = kk*4 + h*2;
                int sw = R & 7;
                int4 wa = *(const int4*)&lA[R*32 + ((ch0 ^ sw) << 2)];
                int4 wb = *(const int4*)&lA[R*32 + (((ch0+1) ^ sw) << 2)];
                unsigned w0 = (unsigned)wa.x, w1 = (unsigned)wa.y, w2 = (unsigned)wa.z, w3 = (unsigned)wa.w;
                unsigned w4 = (unsigned)wb.x, w5 = (unsigned)wb.y, w6 = (unsigned)wb.z, w7 = (unsigned)wb.w;
                bf16x8 Ah = mk_frag((int)__builtin_amdgcn_perm(w1, w0, 0x07060302u),
                                    (int)__builtin_amdgcn_perm(w3, w2, 0x07060302u),
                                    (int)__builtin_amdgcn_perm(w5, w4, 0x07060302u),
                                    (int)__builtin_amdgcn_perm(w7, w6, 0x07060302u));
                bf16x8 Al = mk_frag((int)__builtin_amdgcn_perm(w1, w0, 0x05040100u),
                                    (int)__builtin_amdgcn_perm(w3, w2, 0x05040100u),
                                    (int)__builtin_amdgcn_perm(w5, w4, 0x05040100u),
                                    (int)__builtin_amdgcn_perm(w7, w6, 0x05040100u));
                #pragma unroll
                for (int j2 = 0; j2 < 2; ++j2) {
                    acc[mt2][j2] = __builtin_amdgcn_mfma_f32_32x32x16_bf16(Ah, Bh[j2], acc[mt2][j2], 0, 0, 0);
                    acc[mt2][j2] = __builtin_amdgcn_mfma_f32_32x32x16_bf16(Ah, Bl[j2], acc[mt2][j2], 0, 0, 0);
                    acc[mt2][j2] = __builtin_amdgcn_mfma_f32_32x32x16_bf16(Al, Bh[j2], acc[mt2][j2], 0, 0, 0);
                }
            }
        }
        __syncthreads();
    }
    // epilogue: C/D layout col=lane&31, row=(reg&3)+8*(reg>>2)+4*(lane>>5)
    float* pp = partial + (size_t)ks*65536;
    #pragma unroll
    for (int mt2 = 0; mt2 < 2; ++mt2) {
        #pragma unroll
        for (int j2 = 0; j2 < 2; ++j2) {
            int n = n0 + nw*64 + j2*32 + l32;
            int mb = m0 + mw*64 + mt2*32 + 4*h;
            #pragma unroll
            for (int q = 0; q < 16; ++q) {
                int m = mb + (q & 3) + 8*(q >> 2);
                pp[m*256 + n] = acc[mt2][j2][q];
            }
        }
    }
}

// ---------------- K5: reduce partials + bias + relu + final GEMV + bias + relu ----
__global__ __launch_bounds__(256) void k_final(
        const float* __restrict__ partial, const float* __restrict__ bd1,
        const float* __restrict__ Wd2, const float* __restrict__ bd2,
        float* __restrict__ out) {
    __shared__ float row[256];
    const int m = blockIdx.x, t = threadIdx.x;
    float acc = 0.f;
    const float* p = partial + (size_t)m*256 + t;
    #pragma unroll 8
    for (int kc = 0; kc < 128; ++kc) acc += p[(size_t)kc*65536];
    row[t] = fmaxf(acc + bd1[t], 0.f);
    __syncthreads();
    if (t < 64) {
        float o = bd2[t];
        #pragma unroll 8
        for (int n = 0; n < 256; ++n) o = fmaf(row[n], Wd2[n*64 + t], o);
        out[m*64 + t] = fmaxf(o, 0.f);
    }
}

extern "C" void kernel_launch(void* const* d_in, const int* in_sizes, int n_in,
                              void* d_out, int out_size, void* d_ws, size_t ws_size,
                              hipStream_t stream) {
    const float* x       = (const float*)d_in[0];
    const float* W1      = (const float*)d_in[1];
    const float* b1      = (const float*)d_in[2];
    const float* W2      = (const float*)d_in[3];
    const float* b2      = (const float*)d_in[4];
    const float* scaling = (const float*)d_in[5];
    const float* Wd1     = (const float*)d_in[6];
    const float* bd1     = (const float*)d_in[7];
    const float* Wd2     = (const float*)d_in[8];
    const float* bd2     = (const float*)d_in[9];
    float* out = (float*)d_out;

    char* ws = (char*)d_ws;
    float2* v0 = (float2*)(ws + 0);                        //  64 KB
    float2* U1 = (float2*)(ws + 65536);                    // 128 KB
    unsigned int* state = (unsigned int*)(ws + (1u<<20));  //  64 MB: half2 -> packed bf16 probs
    float* partial = (float*)(ws + (1u<<20) + (size_t)64*1024*1024); // 32 MB

    hipLaunchKernelGGL(k_encoder, dim3(256), dim3(128), 0, stream,
                       x, W1, b1, W2, b2, scaling, v0, U1);
    hipLaunchKernelGGL(k_sim1, dim3(4096), dim3(256), 0, stream, v0, U1, state);
    hipLaunchKernelGGL(k_sim2, dim3(4096), dim3(256), 0, stream, U1, state);
    hipLaunchKernelGGL(k_gemm, dim3(128, 2, 2), dim3(256), 0, stream,
                       state, Wd1, partial);
    hipLaunchKernelGGL(k_final, dim3(256), dim3(256), 0, stream,
                       partial, bd1, Wd2, bd2, out);
}

// Round 5
// 235.947 us; speedup vs baseline: 1.9737x; 1.0119x over previous
//
#include <hip/hip_runtime.h>
#include <hip/hip_fp16.h>

#define PI_F 3.14159265358979323846f

typedef __attribute__((ext_vector_type(8))) _Float16 f16x8;
typedef __attribute__((ext_vector_type(16))) float f32x16;
typedef __attribute__((ext_vector_type(2))) float v2f;

// ---------- packed-fp32 complex helpers (v_pk_fma_f32) ----------
__device__ __forceinline__ v2f pfma(v2f a, v2f b, v2f c) {
    return __builtin_elementwise_fma(a, b, c);
}
__device__ __forceinline__ v2f vswap(v2f a) { return __builtin_shufflevector(a, a, 1, 0); }
__device__ __forceinline__ v2f vsplat(float x) { v2f r; r.x = x; r.y = x; return r; }
__device__ __forceinline__ v2f mkc(v2f u) { v2f r; r.x = -u.y; r.y = u.y; return r; }
__device__ __forceinline__ v2f cmul(v2f a, v2f b) {
    return pfma(mkc(a), vswap(b), vsplat(a.x) * b);
}
__device__ __forceinline__ void gate_pk(v2f& a0, v2f& a1,
        float x00, float x01, float x10, float x11,
        v2f c00, v2f c01, v2f c10, v2f c11) {
    v2f a0s = vswap(a0), a1s = vswap(a1);
    v2f n0 = vsplat(x00) * a0;
    n0 = pfma(c00, a0s, n0);
    n0 = pfma(vsplat(x01), a1, n0);
    n0 = pfma(c01, a1s, n0);
    v2f n1 = vsplat(x10) * a0;
    n1 = pfma(c10, a0s, n1);
    n1 = pfma(vsplat(x11), a1, n1);
    n1 = pfma(c11, a1s, n1);
    a0 = n0; a1 = n1;
}

__device__ __forceinline__ unsigned f2bf_rn(float x) {
    unsigned u = __float_as_uint(x);
    return (u + 0x7fffu + ((u >> 16) & 1u)) >> 16;
}

// async global->LDS, 16B per lane; LDS dest = wave-uniform base + lane*16
__device__ __forceinline__ void gll16(const void* g, void* l) {
    __builtin_amdgcn_global_load_lds(
        (const __attribute__((address_space(1))) void*)g,
        (__attribute__((address_space(3))) void*)l, 16, 0, 0);
}

// ---------------- K1: encoder MLP -> U3 matrices ----------------
__global__ __launch_bounds__(128) void k_encoder(
        const float* __restrict__ x, const float* __restrict__ W1,
        const float* __restrict__ b1, const float* __restrict__ W2,
        const float* __restrict__ b2, const float* __restrict__ scaling,
        float2* __restrict__ v0, float2* __restrict__ U1) {
    __shared__ float xr[64];
    __shared__ float h[128];
    __shared__ float ang[96];
    const int b = blockIdx.x, t = threadIdx.x;
    if (t < 64) xr[t] = x[b*64 + t];
    __syncthreads();
    {
        float acc = b1[t];
        #pragma unroll 8
        for (int f = 0; f < 64; ++f) acc = fmaf(xr[f], W1[f*128 + t], acc);
        h[t] = fmaxf(acc, 0.f);
    }
    __syncthreads();
    if (t < 96) {
        float acc = b2[t];
        #pragma unroll 8
        for (int f = 0; f < 128; ++f) acc = fmaf(h[f], W2[f*96 + t], acc);
        int q = (t/3) & 15;
        ang[t] = tanhf(acc) * scaling[q] * PI_F;
    }
    __syncthreads();
    if (t < 32) {
        int l = t >> 4, q = t & 15;
        const float* a = ang + l*48 + q*3;
        float st, ct, sp, cp, sl, cl;
        sincosf(a[0]*0.5f, &st, &ct);
        sincosf(a[1]*0.5f, &sp, &cp);
        sincosf(a[2]*0.5f, &sl, &cl);
        float2 A00 = make_float2( cp*ct,  sp*st);
        float2 A01 = make_float2(-sp*ct, -cp*st);
        float2 A10 = make_float2( sp*ct, -cp*st);
        float2 A11 = make_float2( cp*ct, -sp*st);
        float2 e0 = make_float2(cl, -sl), e1 = make_float2(cl, sl);
        float2 r00 = make_float2(e0.x*A00.x - e0.y*A00.y, e0.x*A00.y + e0.y*A00.x);
        float2 r01 = make_float2(e0.x*A01.x - e0.y*A01.y, e0.x*A01.y + e0.y*A01.x);
        float2 r10 = make_float2(e1.x*A10.x - e1.y*A10.y, e1.x*A10.y + e1.y*A10.x);
        float2 r11 = make_float2(e1.x*A11.x - e1.y*A11.y, e1.x*A11.y + e1.y*A11.x);
        if (l == 0) {
            float2* v = v0 + (b*16 + q)*2;
            v[0] = r00;
            v[1] = r10;
        } else {
            float2* u = U1 + (b*16 + q)*4;
            u[0] = r00; u[1] = r01;
            u[2] = r10; u[3] = r11;
        }
    }
}

// ---------------- K2 fused: sim1 (blocks 0..4095) + Wd1 conv/transpose (4096..5119) ----
union SimConvLds {
    v2f amp[4368];
    _Float16 wt[64][260];   // [n-local][k-local] padded
};

__global__ __launch_bounds__(256) void k_sim1conv(
        const float2* __restrict__ v0, const float2* __restrict__ U1,
        unsigned int* __restrict__ state,
        const float* __restrict__ Wd1, _Float16* __restrict__ Wt) {
    __shared__ SimConvLds lds;
    const int t = threadIdx.x;
    if (blockIdx.x >= 4096) {
        // ---- conv: Wd1 [65536k][256n] fp32 -> Wt [256n][65536k] fp16 (x64 scale) ----
        const int cb = blockIdx.x - 4096;        // 0..1023
        const int kb = (cb >> 2) * 256;          // k tile of 256
        const int nb = (cb & 3) * 64;            // n tile of 64
        #pragma unroll
        for (int it = 0; it < 16; ++it) {
            int idx = t + it*256;                // 4096 float4 loads
            int kr = idx >> 4;                   // 0..255
            int nc = (idx & 15) * 4;             // 0..60
            float4 w = *(const float4*)(Wd1 + (size_t)(kb + kr)*256 + nb + nc);
            lds.wt[nc+0][kr] = (_Float16)(w.x * 64.f);
            lds.wt[nc+1][kr] = (_Float16)(w.y * 64.f);
            lds.wt[nc+2][kr] = (_Float16)(w.z * 64.f);
            lds.wt[nc+3][kr] = (_Float16)(w.w * 64.f);
        }
        __syncthreads();
        const int n = t >> 2, ck = t & 3;        // row n, 64-k chunk ck
        _Float16* dst = Wt + ((size_t)(nb + n) << 16) + kb + ck*64;
        #pragma unroll
        for (int i = 0; i < 8; ++i) {
            uint2 lo = *(const uint2*)&lds.wt[n][ck*64 + i*8];
            uint2 hi = *(const uint2*)&lds.wt[n][ck*64 + i*8 + 4];
            int4 v = make_int4((int)lo.x, (int)lo.y, (int)hi.x, (int)hi.y);
            *(int4*)(dst + i*8) = v;
        }
        return;
    }
    // ---- sim1: product state + layer1 gates on qubits 15..4, 3 register phases ----
    const int b = blockIdx.x >> 4, c = blockIdx.x & 15;
    const v2f* v = (const v2f*)(v0 + b*32);
    const v2f* ub = (const v2f*)(U1 + b*64);
    const int zbase = (c << 12) | (t << 4);
    const int zz = zbase ^ (zbase >> 1);
    v2f F; F.x = 1.f; F.y = 0.f;
    #pragma unroll
    for (int p = 4; p <= 11; ++p)
        F = cmul(F, v[(15-p)*2 + ((zz>>p)&1)]);
    F = cmul(F, v[6 + ((c ^ (c>>1)) & 1)]);          // p=12
    F = cmul(F, v[4 + (((c>>1) ^ (c>>2)) & 1)]);     // p=13
    const int c2 = (c>>2)&1, c3 = (c>>3)&1;
    v2f H0 = cmul(cmul(F, v[2 + (c2^c3)]),   v[c3]);
    v2f H1 = cmul(cmul(F, v[2 + (c2^c3^1)]), v[c3^1]);
    const int t4 = t & 1;
    v2f a[16];
    #pragma unroll
    for (int i = 0; i < 16; ++i) {
        int i0 = i&1, i1 = (i>>1)&1, i2 = (i>>2)&1, i3 = i>>3;
        v2f lo = cmul(cmul(v[30 + (i0^i1)], v[28 + (i1^i2)]),
                      cmul(v[26 + (i2^i3)], v[24 + (i3^t4)]));
        a[i] = cmul(lo, i0 ? H1 : H0);
    }
    #pragma unroll
    for (int p = 0; p < 4; ++p) {
        const v2f u00 = ub[(15-p)*4+0], u01 = ub[(15-p)*4+1];
        const v2f u10 = ub[(15-p)*4+2], u11 = ub[(15-p)*4+3];
        const v2f c00 = mkc(u00), c01 = mkc(u01), c10 = mkc(u10), c11 = mkc(u11);
        #pragma unroll
        for (int i = 0; i < 16; ++i)
            if (!(i & (1<<p)))
                gate_pk(a[i], a[i | (1<<p)], u00.x, u01.x, u10.x, u11.x, c00, c01, c10, c11);
    }
    {
        const int ph1 = 17*t + (t>>4);
        #pragma unroll
        for (int i = 0; i < 16; ++i) lds.amp[ph1 + i] = a[i];
    }
    __syncthreads();
    {
        const int ph2 = (t & 15) + 273*(t >> 4);
        #pragma unroll
        for (int j = 0; j < 16; ++j) a[j] = lds.amp[ph2 + 17*j];
        #pragma unroll
        for (int p = 0; p < 4; ++p) {
            const v2f u00 = ub[(11-p)*4+0], u01 = ub[(11-p)*4+1];
            const v2f u10 = ub[(11-p)*4+2], u11 = ub[(11-p)*4+3];
            const v2f c00 = mkc(u00), c01 = mkc(u01), c10 = mkc(u10), c11 = mkc(u11);
            #pragma unroll
            for (int j = 0; j < 16; ++j)
                if (!(j & (1<<p)))
                    gate_pk(a[j], a[j | (1<<p)], u00.x, u01.x, u10.x, u11.x, c00, c01, c10, c11);
        }
        #pragma unroll
        for (int j = 0; j < 16; ++j) lds.amp[ph2 + 17*j] = a[j];
    }
    __syncthreads();
    {
        const int ph3 = t + (t >> 4);
        #pragma unroll
        for (int j = 0; j < 16; ++j) a[j] = lds.amp[ph3 + 273*j];
        #pragma unroll
        for (int p = 0; p < 4; ++p) {
            const v2f u00 = ub[(7-p)*4+0], u01 = ub[(7-p)*4+1];
            const v2f u10 = ub[(7-p)*4+2], u11 = ub[(7-p)*4+3];
            const v2f c00 = mkc(u00), c01 = mkc(u01), c10 = mkc(u10), c11 = mkc(u11);
            #pragma unroll
            for (int j = 0; j < 16; ++j)
                if (!(j & (1<<p)))
                    gate_pk(a[j], a[j | (1<<p)], u00.x, u01.x, u10.x, u11.x, c00, c01, c10, c11);
        }
        const size_t base = (size_t)b*65536 + (c << 12) + t;
        #pragma unroll
        for (int j = 0; j < 16; ++j) {
            __half2 hv = __floats2half2_rn(a[j].x, a[j].y);
            unsigned int u; __builtin_memcpy(&u, &hv, 4);
            state[base + (j << 8)] = u;
        }
    }
}

// ---------------- K3: qubits 3..0 (bits 12-15) + probs -> fp16 A (x4096 scale) ----
__global__ __launch_bounds__(256) void k_sim2(
        const float2* __restrict__ U1, const unsigned int* __restrict__ state,
        _Float16* __restrict__ A) {
    const int b = blockIdx.x >> 4, jc = blockIdx.x & 15;
    const int tid = threadIdx.x;
    const int j = jc*256 + tid;
    const v2f* ub = (const v2f*)(U1 + b*64);
    const size_t sb = (size_t)b*65536;
    v2f a[16];
    #pragma unroll
    for (int s = 0; s < 16; ++s) {
        unsigned int u = state[sb + (s << 12) + j];
        __half2 hv; __builtin_memcpy(&hv, &u, 4);
        float2 f = __half22float2(hv);
        a[s].x = f.x; a[s].y = f.y;
    }
    #pragma unroll
    for (int ss = 0; ss < 4; ++ss) {
        const v2f u00 = ub[(3-ss)*4+0], u01 = ub[(3-ss)*4+1];
        const v2f u10 = ub[(3-ss)*4+2], u11 = ub[(3-ss)*4+3];
        const v2f c00 = mkc(u00), c01 = mkc(u01), c10 = mkc(u10), c11 = mkc(u11);
        #pragma unroll
        for (int s = 0; s < 16; ++s)
            if (!(s & (1<<ss)))
                gate_pk(a[s], a[s | (1<<ss)], u00.x, u01.x, u10.x, u11.x, c00, c01, c10, c11);
    }
    #pragma unroll
    for (int s = 0; s < 16; ++s) {
        float pr = fmaf(a[s].x, a[s].x, a[s].y * a[s].y) * 4096.f;
        A[sb + (s << 12) + j] = (_Float16)pr;
    }
}

// ---------------- K4: single-pass fp16 MFMA GEMM, split-K ----------------
// partial[ks][m][n] (bf16) = A[m, ks*256:+256] @ Wt[n, ks*256:+256]^T
// tile 128m x 128n x 256k, BK=64; grid (256 ks, 2 nt, 2 mt) = 1024 blocks.
__global__ __launch_bounds__(256, 4) void k_gemm(
        const _Float16* __restrict__ A, const _Float16* __restrict__ Bt,
        unsigned short* __restrict__ partial) {
    __shared__ _Float16 lA[128*64];   // [m][64k], row=128B=8 chunks, chunk c at c^(r&7)
    __shared__ _Float16 lB[128*64];   // [n][64k], same swizzle
    const int ks = blockIdx.x, nt = blockIdx.y, mt = blockIdx.z;
    const int k0 = ks*256, n0 = nt*128, m0 = mt*128;
    const int tid = threadIdx.x, wave = tid >> 6, lane = tid & 63;
    const int mw = wave >> 1, nw = wave & 1;
    const int h = lane >> 5, l32 = lane & 31;
    f32x16 acc[2][2] = {};
    for (int s = 0; s < 4; ++s) {
        const int kb = k0 + s*64;
        #pragma unroll
        for (int i = 0; i < 4; ++i) {
            int ia = wave*4 + i;                 // 0..15, 8 rows each
            int r = ia*8 + (lane >> 3);
            int cch = (lane & 7) ^ (r & 7);
            gll16(A  + (size_t)(m0 + r)*65536 + kb + cch*8, &lA[ia*512]);
            gll16(Bt + (size_t)(n0 + r)*65536 + kb + cch*8, &lB[ia*512]);
        }
        __syncthreads();
        #pragma unroll
        for (int kk = 0; kk < 4; ++kk) {
            const int ch = kk*2 + h;
            f16x8 af[2], bf[2];
            #pragma unroll
            for (int x = 0; x < 2; ++x) {
                int rA = mw*64 + x*32 + l32;
                af[x] = *(const f16x8*)&lA[rA*64 + ((ch ^ (rA & 7)) << 3)];
                int rB = nw*64 + x*32 + l32;
                bf[x] = *(const f16x8*)&lB[rB*64 + ((ch ^ (rB & 7)) << 3)];
            }
            #pragma unroll
            for (int i = 0; i < 2; ++i)
                #pragma unroll
                for (int jj = 0; jj < 2; ++jj)
                    acc[i][jj] = __builtin_amdgcn_mfma_f32_32x32x16_f16(af[i], bf[jj], acc[i][jj], 0, 0, 0);
        }
        __syncthreads();
    }
    // epilogue: C/D layout col=lane&31, row=(reg&3)+8*(reg>>2)+4*(lane>>5); store bf16
    unsigned short* pp = partial + (size_t)ks*65536;
    #pragma unroll
    for (int i = 0; i < 2; ++i) {
        #pragma unroll
        for (int jj = 0; jj < 2; ++jj) {
            int n = n0 + nw*64 + jj*32 + l32;
            int mb = m0 + mw*64 + i*32 + 4*h;
            #pragma unroll
            for (int q = 0; q < 16; ++q) {
                int m = mb + (q & 3) + 8*(q >> 2);
                pp[m*256 + n] = (unsigned short)f2bf_rn(acc[i][jj][q]);
            }
        }
    }
}

// ---------------- K5: reduce bf16 partials (x 2^-18) + bias + relu + GEMV ----
__global__ __launch_bounds__(256) void k_final(
        const unsigned short* __restrict__ partial, const float* __restrict__ bd1,
        const float* __restrict__ Wd2, const float* __restrict__ bd2,
        float* __restrict__ out) {
    __shared__ float row[256];
    const int m = blockIdx.x, t = threadIdx.x;
    if (t < 128) {
        const unsigned* p = (const unsigned*)partial + m*128 + t;  // n = 2t, 2t+1
        float s0 = 0.f, s1 = 0.f;
        #pragma unroll 8
        for (int kc = 0; kc < 256; ++kc) {
            unsigned u = p[(size_t)kc*32768];
            s0 += __uint_as_float(u << 16);
            s1 += __uint_as_float(u & 0xffff0000u);
        }
        const float SC = 1.f / 262144.f;   // undo 4096 * 64
        row[2*t]   = fmaxf(fmaf(s0, SC, bd1[2*t]),   0.f);
        row[2*t+1] = fmaxf(fmaf(s1, SC, bd1[2*t+1]), 0.f);
    }
    __syncthreads();
    if (t < 64) {
        float o = bd2[t];
        #pragma unroll 8
        for (int n = 0; n < 256; ++n) o = fmaf(row[n], Wd2[n*64 + t], o);
        out[m*64 + t] = fmaxf(o, 0.f);
    }
}

extern "C" void kernel_launch(void* const* d_in, const int* in_sizes, int n_in,
                              void* d_out, int out_size, void* d_ws, size_t ws_size,
                              hipStream_t stream) {
    const float* x       = (const float*)d_in[0];
    const float* W1      = (const float*)d_in[1];
    const float* b1      = (const float*)d_in[2];
    const float* W2      = (const float*)d_in[3];
    const float* b2      = (const float*)d_in[4];
    const float* scaling = (const float*)d_in[5];
    const float* Wd1     = (const float*)d_in[6];
    const float* bd1     = (const float*)d_in[7];
    const float* Wd2     = (const float*)d_in[8];
    const float* bd2     = (const float*)d_in[9];
    float* out = (float*)d_out;

    char* ws = (char*)d_ws;
    const size_t MB = 1024*1024;
    float2* v0 = (float2*)(ws + 0);                  //  64 KB
    float2* U1 = (float2*)(ws + 65536);              // 128 KB
    unsigned int* state = (unsigned int*)(ws + MB);  // 64 MB  [1,65)  (fp16 amp pairs)
    unsigned short* partial = (unsigned short*)(ws + MB);  // 32 MB [1,33) overlays dead state
    _Float16* A  = (_Float16*)(ws + 65*MB);          // 32 MB  [65,97)
    _Float16* Wt = (_Float16*)(ws + 97*MB);          // 32 MB  [97,129)

    hipLaunchKernelGGL(k_encoder, dim3(256), dim3(128), 0, stream,
                       x, W1, b1, W2, b2, scaling, v0, U1);
    hipLaunchKernelGGL(k_sim1conv, dim3(5120), dim3(256), 0, stream,
                       v0, U1, state, Wd1, Wt);
    hipLaunchKernelGGL(k_sim2, dim3(4096), dim3(256), 0, stream, U1, state, A);
    hipLaunchKernelGGL(k_gemm, dim3(256, 2, 2), dim3(256), 0, stream, A, Wt, partial);
    hipLaunchKernelGGL(k_final, dim3(256), dim3(256), 0, stream,
                       partial, bd1, Wd2, bd2, out);
}

// Round 6
// 183.735 us; speedup vs baseline: 2.5346x; 1.2842x over previous
//
#include <hip/hip_runtime.h>
#include <hip/hip_fp16.h>

#define PI_F 3.14159265358979323846f

typedef __attribute__((ext_vector_type(8))) _Float16 f16x8;
typedef __attribute__((ext_vector_type(16))) float f32x16;
typedef __attribute__((ext_vector_type(2))) float v2f;

// ---------- packed-fp32 complex helpers (v_pk_fma_f32) ----------
__device__ __forceinline__ v2f pfma(v2f a, v2f b, v2f c) {
    return __builtin_elementwise_fma(a, b, c);
}
__device__ __forceinline__ v2f vswap(v2f a) { return __builtin_shufflevector(a, a, 1, 0); }
__device__ __forceinline__ v2f vsplat(float x) { v2f r; r.x = x; r.y = x; return r; }
__device__ __forceinline__ v2f mkc(v2f u) { v2f r; r.x = -u.y; r.y = u.y; return r; }
__device__ __forceinline__ v2f cmul(v2f a, v2f b) {
    return pfma(mkc(a), vswap(b), vsplat(a.x) * b);
}

__device__ __forceinline__ unsigned f2bf_rn(float x) {
    unsigned u = __float_as_uint(x);
    return (u + 0x7fffu + ((u >> 16) & 1u)) >> 16;
}

union H8 { int4 i4; f16x8 v; };

// async global->LDS, 16B per lane; LDS dest = wave-uniform base + lane*16
__device__ __forceinline__ void gll16(const void* g, void* l) {
    __builtin_amdgcn_global_load_lds(
        (const __attribute__((address_space(1))) void*)g,
        (__attribute__((address_space(3))) void*)l, 16, 0, 0);
}

// ---------------- K1 fused: encoder MLP -> U3; MPS chain DP -> L,R (blocks 0..255)
//                  + Wd1 conv/transpose (blocks 256..1279) ----------------
// amp(z) = sum_{g,y7} L(z0..z7)[g,y7] * R(z8..z15)[g,y7]   (bond 2 + y0 boundary)
// a_p[s] = v_{15-p}[s]; G_p = U1 gate on bit p (= qubit 15-p).
union EncConvLds {
    struct {
        float xr[64]; float h[128]; float ang[96];
        v2f vL[32];   // a_p: vL[(15-p)*2 + s]
        v2f uL[64];   // G_p: uL[(15-p)*4 + z*2 + y]
    } e;
    _Float16 wt[64][260];
};

__global__ __launch_bounds__(256) void k_enc_chain(
        const float* __restrict__ x, const float* __restrict__ W1,
        const float* __restrict__ b1, const float* __restrict__ W2,
        const float* __restrict__ b2, const float* __restrict__ scaling,
        const float* __restrict__ Wd1, _Float16* __restrict__ Wt,
        _Float16* __restrict__ Lb, _Float16* __restrict__ Rb) {
    __shared__ EncConvLds lds;
    const int t = threadIdx.x;
    if (blockIdx.x >= 256) {
        // ---- conv: Wd1 [65536k][256n] fp32 -> Wt [256n][65536k] fp16 (x64 scale) ----
        const int cb = blockIdx.x - 256;         // 0..1023
        const int kb = (cb >> 2) * 256;
        const int nb = (cb & 3) * 64;
        #pragma unroll
        for (int it = 0; it < 16; ++it) {
            int idx = t + it*256;
            int kr = idx >> 4;
            int nc = (idx & 15) * 4;
            float4 w = *(const float4*)(Wd1 + (size_t)(kb + kr)*256 + nb + nc);
            lds.wt[nc+0][kr] = (_Float16)(w.x * 64.f);
            lds.wt[nc+1][kr] = (_Float16)(w.y * 64.f);
            lds.wt[nc+2][kr] = (_Float16)(w.z * 64.f);
            lds.wt[nc+3][kr] = (_Float16)(w.w * 64.f);
        }
        __syncthreads();
        const int n = t >> 2, ck = t & 3;
        _Float16* dst = Wt + ((size_t)(nb + n) << 16) + kb + ck*64;
        #pragma unroll
        for (int i = 0; i < 8; ++i) {
            uint2 lo = *(const uint2*)&lds.wt[n][ck*64 + i*8];
            uint2 hi = *(const uint2*)&lds.wt[n][ck*64 + i*8 + 4];
            int4 v = make_int4((int)lo.x, (int)lo.y, (int)hi.x, (int)hi.y);
            *(int4*)(dst + i*8) = v;
        }
        return;
    }
    // ---- encoder phase ----
    const int b = blockIdx.x;
    if (t < 64) lds.e.xr[t] = x[b*64 + t];
    __syncthreads();
    if (t < 128) {
        float acc = b1[t];
        #pragma unroll 8
        for (int f = 0; f < 64; ++f) acc = fmaf(lds.e.xr[f], W1[f*128 + t], acc);
        lds.e.h[t] = fmaxf(acc, 0.f);
    }
    __syncthreads();
    if (t < 96) {
        float acc = b2[t];
        #pragma unroll 8
        for (int f = 0; f < 128; ++f) acc = fmaf(lds.e.h[f], W2[f*96 + t], acc);
        int q = (t/3) & 15;
        lds.e.ang[t] = tanhf(acc) * scaling[q] * PI_F;
    }
    __syncthreads();
    if (t < 32) {
        int l = t >> 4, q = t & 15;
        const float* a = lds.e.ang + l*48 + q*3;
        float st, ct, sp, cp, sl, cl;
        sincosf(a[0]*0.5f, &st, &ct);
        sincosf(a[1]*0.5f, &sp, &cp);
        sincosf(a[2]*0.5f, &sl, &cl);
        float2 A00 = make_float2( cp*ct,  sp*st);
        float2 A01 = make_float2(-sp*ct, -cp*st);
        float2 A10 = make_float2( sp*ct, -cp*st);
        float2 A11 = make_float2( cp*ct, -sp*st);
        float2 e0 = make_float2(cl, -sl), e1 = make_float2(cl, sl);
        v2f r00; r00.x = e0.x*A00.x - e0.y*A00.y; r00.y = e0.x*A00.y + e0.y*A00.x;
        v2f r01; r01.x = e0.x*A01.x - e0.y*A01.y; r01.y = e0.x*A01.y + e0.y*A01.x;
        v2f r10; r10.x = e1.x*A10.x - e1.y*A10.y; r10.y = e1.x*A10.y + e1.y*A10.x;
        v2f r11; r11.x = e1.x*A11.x - e1.y*A11.y; r11.y = e1.x*A11.y + e1.y*A11.x;
        if (l == 0) {                 // layer-0: U|0> = column 0
            lds.e.vL[q*2 + 0] = r00;
            lds.e.vL[q*2 + 1] = r10;
        } else {                      // layer-1 gates, row-major
            lds.e.uL[q*4 + 0] = r00; lds.e.uL[q*4 + 1] = r01;
            lds.e.uL[q*4 + 2] = r10; lds.e.uL[q*4 + 3] = r11;
        }
    }
    __syncthreads();
    // ---- chain phase: thread t = prefix (z0..z7) for L, suffix (z8..z15) for R ----
    #define AP(p, s) lds.e.vL[(15-(p))*2 + (s)]
    #define GG(p, zv, yv) lds.e.uL[(15-(p))*4 + (zv)*2 + (yv)]
    const float SL = 32.f;
    v2f Lg[2][2];   // [g][y7]
    {
        int z0 = t & 1, z1 = (t >> 1) & 1;
        #pragma unroll
        for (int g = 0; g < 2; ++g)
            #pragma unroll
            for (int y = 0; y < 2; ++y)
                Lg[g][y] = cmul(cmul(GG(0, z0, g), AP(0, g ^ y)), GG(1, z1, y));
        #pragma unroll
        for (int p = 2; p <= 7; ++p) {
            int zp = (t >> p) & 1;
            #pragma unroll
            for (int g = 0; g < 2; ++g) {
                v2f s0 = cmul(Lg[g][0], AP(p-1, 0)) + cmul(Lg[g][1], AP(p-1, 1));
                v2f s1 = cmul(Lg[g][0], AP(p-1, 1)) + cmul(Lg[g][1], AP(p-1, 0));
                Lg[g][0] = cmul(s0, GG(p, zp, 0));
                Lg[g][1] = cmul(s1, GG(p, zp, 1));
            }
        }
    }
    v2f Rg[2][2];   // [g][y7]
    {
        int z15 = (t >> 7) & 1;
        #pragma unroll
        for (int g = 0; g < 2; ++g)
            #pragma unroll
            for (int y14 = 0; y14 < 2; ++y14)
                Rg[g][y14] = cmul(cmul(AP(14, y14 ^ g),     AP(15, g)),     GG(15, z15, 0))
                           + cmul(cmul(AP(14, y14 ^ 1 ^ g), AP(15, 1 ^ g)), GG(15, z15, 1));
        #pragma unroll
        for (int p = 14; p >= 8; --p) {
            int zp = (t >> (p - 8)) & 1;
            #pragma unroll
            for (int g = 0; g < 2; ++g) {
                v2f t0 = cmul(GG(p, zp, 0), Rg[g][0]);
                v2f t1 = cmul(GG(p, zp, 1), Rg[g][1]);
                v2f n0 = cmul(AP(p-1, 0), t0) + cmul(AP(p-1, 1), t1);
                v2f n1 = cmul(AP(p-1, 1), t0) + cmul(AP(p-1, 0), t1);
                Rg[g][0] = n0; Rg[g][1] = n1;
            }
        }
    }
    // ---- store fp16: k = g*2 + y7 ; B-operand has the complex-mul signs prebaked ----
    float lre[4] = {Lg[0][0].x, Lg[0][1].x, Lg[1][0].x, Lg[1][1].x};
    float lim[4] = {Lg[0][0].y, Lg[0][1].y, Lg[1][0].y, Lg[1][1].y};
    float rre[4] = {Rg[0][0].x, Rg[0][1].x, Rg[1][0].x, Rg[1][1].x};
    float rim[4] = {Rg[0][0].y, Rg[0][1].y, Rg[1][0].y, Rg[1][1].y};
    H8 hre, him, hr;
    #pragma unroll
    for (int k = 0; k < 4; ++k) {
        hre.v[k]   = (_Float16)(SL * lre[k]);
        hre.v[4+k] = (_Float16)(-SL * lim[k]);
        him.v[k]   = (_Float16)(SL * lim[k]);
        him.v[4+k] = (_Float16)(SL * lre[k]);
        hr.v[k]    = (_Float16)(SL * rre[k]);
        hr.v[4+k]  = (_Float16)(SL * rim[k]);
    }
    *(int4*)(Lb + ((size_t)b*512 + t)*8)       = hre.i4;   // re-plane col
    *(int4*)(Lb + ((size_t)b*512 + 256 + t)*8) = him.i4;   // im-plane col
    *(int4*)(Rb + ((size_t)b*256 + t)*8)       = hr.i4;
    #undef AP
    #undef GG
}

// ---------------- K2: amp + probs via MFMA ----------------
// per b: D[256 zh][512 (zl|plane)] = R[256x8] @ Lcols[8x512] (K zero-padded to 16);
// p*4096 = (Dre^2 + Dim^2) * 2^-8 -> fp16 A[b][zh*256+zl]
__global__ __launch_bounds__(256) void k_amp(
        const _Float16* __restrict__ Lb, const _Float16* __restrict__ Rb,
        _Float16* __restrict__ A) {
    __shared__ _Float16 lR[256*8];
    __shared__ _Float16 lL[512*8];
    const int b = blockIdx.x, t = threadIdx.x;
    {
        const float4* gl = (const float4*)(Lb + (size_t)b*512*8);
        float4* sl = (float4*)lL;
        sl[t] = gl[t];
        sl[t+256] = gl[t+256];
        ((float4*)lR)[t] = ((const float4*)(Rb + (size_t)b*256*8))[t];
    }
    __syncthreads();
    const int wave = t >> 6, lane = t & 63, h = lane >> 5, l32 = lane & 31;
    f16x8 zf = {};
    _Float16* Aout = A + ((size_t)b << 16);
    #pragma unroll
    for (int mt2 = 0; mt2 < 2; ++mt2) {
        const int zh0 = (wave*2 + mt2)*32;
        f16x8 af = h ? zf : *(const f16x8*)&lR[(zh0 + l32)*8];
        #pragma unroll
        for (int j = 0; j < 8; ++j) {
            f16x8 bre = h ? zf : *(const f16x8*)&lL[(j*32 + l32)*8];
            f16x8 bim = h ? zf : *(const f16x8*)&lL[(256 + j*32 + l32)*8];
            f32x16 zc = {};
            f32x16 dre = __builtin_amdgcn_mfma_f32_32x32x16_f16(af, bre, zc, 0, 0, 0);
            f32x16 dim = __builtin_amdgcn_mfma_f32_32x32x16_f16(af, bim, zc, 0, 0, 0);
            #pragma unroll
            for (int q = 0; q < 16; ++q) {
                float p = fmaf(dre[q], dre[q], dim[q]*dim[q]) * 0.00390625f;  // 2^-8
                int row = zh0 + 4*h + (q & 3) + 8*(q >> 2);
                Aout[row*256 + j*32 + l32] = (_Float16)p;
            }
        }
    }
}

// ---------------- K3: single-pass fp16 MFMA GEMM, split-K ----------------
// partial[ks][m][n] (bf16) = A[m, ks*256:+256] @ Wt[n, ks*256:+256]^T
// tile 128m x 128n x 256k, BK=64; grid (256 ks, 2 nt, 2 mt) = 1024 blocks.
__global__ __launch_bounds__(256, 4) void k_gemm(
        const _Float16* __restrict__ A, const _Float16* __restrict__ Bt,
        unsigned short* __restrict__ partial) {
    __shared__ _Float16 lA[128*64];   // [m][64k], row=128B=8 chunks, chunk c at c^(r&7)
    __shared__ _Float16 lB[128*64];
    const int ks = blockIdx.x, nt = blockIdx.y, mt = blockIdx.z;
    const int k0 = ks*256, n0 = nt*128, m0 = mt*128;
    const int tid = threadIdx.x, wave = tid >> 6, lane = tid & 63;
    const int mw = wave >> 1, nw = wave & 1;
    const int h = lane >> 5, l32 = lane & 31;
    f32x16 acc[2][2] = {};
    for (int s = 0; s < 4; ++s) {
        const int kb = k0 + s*64;
        #pragma unroll
        for (int i = 0; i < 4; ++i) {
            int ia = wave*4 + i;
            int r = ia*8 + (lane >> 3);
            int cch = (lane & 7) ^ (r & 7);
            gll16(A  + (size_t)(m0 + r)*65536 + kb + cch*8, &lA[ia*512]);
            gll16(Bt + (size_t)(n0 + r)*65536 + kb + cch*8, &lB[ia*512]);
        }
        __syncthreads();
        #pragma unroll
        for (int kk = 0; kk < 4; ++kk) {
            const int ch = kk*2 + h;
            f16x8 af[2], bf[2];
            #pragma unroll
            for (int xx = 0; xx < 2; ++xx) {
                int rA = mw*64 + xx*32 + l32;
                af[xx] = *(const f16x8*)&lA[rA*64 + ((ch ^ (rA & 7)) << 3)];
                int rB = nw*64 + xx*32 + l32;
                bf[xx] = *(const f16x8*)&lB[rB*64 + ((ch ^ (rB & 7)) << 3)];
            }
            #pragma unroll
            for (int i = 0; i < 2; ++i)
                #pragma unroll
                for (int jj = 0; jj < 2; ++jj)
                    acc[i][jj] = __builtin_amdgcn_mfma_f32_32x32x16_f16(af[i], bf[jj], acc[i][jj], 0, 0, 0);
        }
        __syncthreads();
    }
    unsigned short* pp = partial + (size_t)ks*65536;
    #pragma unroll
    for (int i = 0; i < 2; ++i) {
        #pragma unroll
        for (int jj = 0; jj < 2; ++jj) {
            int n = n0 + nw*64 + jj*32 + l32;
            int mb = m0 + mw*64 + i*32 + 4*h;
            #pragma unroll
            for (int q = 0; q < 16; ++q) {
                int m = mb + (q & 3) + 8*(q >> 2);
                pp[m*256 + n] = (unsigned short)f2bf_rn(acc[i][jj][q]);
            }
        }
    }
}

// ---------------- K4: reduce bf16 partials (x 2^-18) + bias + relu + GEMV ----
__global__ __launch_bounds__(256) void k_final(
        const unsigned short* __restrict__ partial, const float* __restrict__ bd1,
        const float* __restrict__ Wd2, const float* __restrict__ bd2,
        float* __restrict__ out) {
    __shared__ float row[256];
    const int m = blockIdx.x, t = threadIdx.x;
    if (t < 128) {
        const unsigned* p = (const unsigned*)partial + m*128 + t;
        float s0 = 0.f, s1 = 0.f;
        #pragma unroll 8
        for (int kc = 0; kc < 256; ++kc) {
            unsigned u = p[(size_t)kc*32768];
            s0 += __uint_as_float(u << 16);
            s1 += __uint_as_float(u & 0xffff0000u);
        }
        const float SC = 1.f / 262144.f;   // undo 4096 (A) * 64 (Wt)
        row[2*t]   = fmaxf(fmaf(s0, SC, bd1[2*t]),   0.f);
        row[2*t+1] = fmaxf(fmaf(s1, SC, bd1[2*t+1]), 0.f);
    }
    __syncthreads();
    if (t < 64) {
        float o = bd2[t];
        #pragma unroll 8
        for (int n = 0; n < 256; ++n) o = fmaf(row[n], Wd2[n*64 + t], o);
        out[m*64 + t] = fmaxf(o, 0.f);
    }
}

extern "C" void kernel_launch(void* const* d_in, const int* in_sizes, int n_in,
                              void* d_out, int out_size, void* d_ws, size_t ws_size,
                              hipStream_t stream) {
    const float* x       = (const float*)d_in[0];
    const float* W1      = (const float*)d_in[1];
    const float* b1      = (const float*)d_in[2];
    const float* W2      = (const float*)d_in[3];
    const float* b2      = (const float*)d_in[4];
    const float* scaling = (const float*)d_in[5];
    const float* Wd1     = (const float*)d_in[6];
    const float* bd1     = (const float*)d_in[7];
    const float* Wd2     = (const float*)d_in[8];
    const float* bd2     = (const float*)d_in[9];
    float* out = (float*)d_out;

    char* ws = (char*)d_ws;
    const size_t MB = 1024*1024;
    _Float16* Lb = (_Float16*)(ws + 0);              //  2 MB  [b][512][8]
    _Float16* Rb = (_Float16*)(ws + 2*MB);           //  1 MB  [b][256][8]
    _Float16* A  = (_Float16*)(ws + 4*MB);           // 32 MB  [4,36)
    _Float16* Wt = (_Float16*)(ws + 36*MB);          // 32 MB  [36,68)
    unsigned short* partial = (unsigned short*)(ws + 68*MB);  // 32 MB [68,100)

    hipLaunchKernelGGL(k_enc_chain, dim3(1280), dim3(256), 0, stream,
                       x, W1, b1, W2, b2, scaling, Wd1, Wt, Lb, Rb);
    hipLaunchKernelGGL(k_amp, dim3(256), dim3(256), 0, stream, Lb, Rb, A);
    hipLaunchKernelGGL(k_gemm, dim3(256, 2, 2), dim3(256), 0, stream, A, Wt, partial);
    hipLaunchKernelGGL(k_final, dim3(256), dim3(256), 0, stream,
                       partial, bd1, Wd2, bd2, out);
}

// Round 7
// 172.410 us; speedup vs baseline: 2.7011x; 1.0657x over previous
//
#include <hip/hip_runtime.h>
#include <hip/hip_fp16.h>

#define PI_F 3.14159265358979323846f

typedef __attribute__((ext_vector_type(8))) _Float16 f16x8;
typedef __attribute__((ext_vector_type(16))) float f32x16;
typedef __attribute__((ext_vector_type(2))) float v2f;

// ---------- packed-fp32 complex helpers (v_pk_fma_f32) ----------
__device__ __forceinline__ v2f pfma(v2f a, v2f b, v2f c) {
    return __builtin_elementwise_fma(a, b, c);
}
__device__ __forceinline__ v2f vswap(v2f a) { return __builtin_shufflevector(a, a, 1, 0); }
__device__ __forceinline__ v2f vsplat(float x) { v2f r; r.x = x; r.y = x; return r; }
__device__ __forceinline__ v2f mkc(v2f u) { v2f r; r.x = -u.y; r.y = u.y; return r; }
__device__ __forceinline__ v2f cmul(v2f a, v2f b) {
    return pfma(mkc(a), vswap(b), vsplat(a.x) * b);
}

__device__ __forceinline__ unsigned f2bf_rn(float x) {
    unsigned u = __float_as_uint(x);
    return (u + 0x7fffu + ((u >> 16) & 1u)) >> 16;
}

union H8 { int4 i4; f16x8 v; };

// async global->LDS, 16B per lane; LDS dest = wave-uniform base + lane*16
__device__ __forceinline__ void gll16(const void* g, void* l) {
    __builtin_amdgcn_global_load_lds(
        (const __attribute__((address_space(1))) void*)g,
        (__attribute__((address_space(3))) void*)l, 16, 0, 0);
}

// ---------------- K1 fused: [blocks 0..255]  encoder -> U3 -> MPS chain -> amp MFMA -> A[b]
//                             [blocks 256..1279] Wd1 conv/transpose -> Wt ----------------
// amp(z) = sum_{g,y7} L(z0..z7)[g,y7] * R(z8..z15)[g,y7]  (bond 2 + y0 boundary)
union PreLds {
    struct {
        float xr[64]; float h[128]; float ang[96];
        v2f vL[32];            // a_p: vL[(15-p)*2 + s]
        v2f uL[64];            // G_p: uL[(15-p)*4 + z*2 + y]
        _Float16 lR[256*8];    // R rows (4 KB)
        _Float16 lL[512*8];    // L re-plane rows 0..255, im-plane 256..511 (8 KB)
    } e;
    _Float16 wt[64][260];      // conv transpose tile (33.3 KB)
};

__global__ __launch_bounds__(256) void k_pre(
        const float* __restrict__ x, const float* __restrict__ W1,
        const float* __restrict__ b1, const float* __restrict__ W2,
        const float* __restrict__ b2, const float* __restrict__ scaling,
        const float* __restrict__ Wd1, _Float16* __restrict__ Wt,
        _Float16* __restrict__ A) {
    __shared__ PreLds lds;
    const int t = threadIdx.x;
    if (blockIdx.x >= 256) {
        // ---- conv: Wd1 [65536k][256n] fp32 -> Wt [256n][65536k] fp16 (x64 scale) ----
        const int cb = blockIdx.x - 256;         // 0..1023
        const int kb = (cb >> 2) * 256;          // k tile of 256
        const int nb = (cb & 3) * 64;            // n tile of 64
        #pragma unroll
        for (int it = 0; it < 16; ++it) {
            int idx = t + it*256;
            int kr = idx >> 4;
            int nc = (idx & 15) * 4;
            float4 w = *(const float4*)(Wd1 + (size_t)(kb + kr)*256 + nb + nc);
            lds.wt[nc+0][kr] = (_Float16)(w.x * 64.f);
            lds.wt[nc+1][kr] = (_Float16)(w.y * 64.f);
            lds.wt[nc+2][kr] = (_Float16)(w.z * 64.f);
            lds.wt[nc+3][kr] = (_Float16)(w.w * 64.f);
        }
        __syncthreads();
        // writes: per instruction 2 rows x 512B contiguous
        const int wv = t >> 6, ln = t & 63;
        const int u = ln & 31;                   // 16B unit within row
        #pragma unroll
        for (int r = 0; r < 8; ++r) {
            int n = r*8 + wv*2 + (ln >> 5);
            int4 hh = *(const int4*)&lds.wt[n][u*8];
            *(int4*)(Wt + ((size_t)(nb + n) << 16) + kb + u*8) = hh;
        }
        return;
    }
    // ---- encoder phase ----
    const int b = blockIdx.x;
    if (t < 64) lds.e.xr[t] = x[b*64 + t];
    __syncthreads();
    if (t < 128) {
        float acc = b1[t];
        #pragma unroll 8
        for (int f = 0; f < 64; ++f) acc = fmaf(lds.e.xr[f], W1[f*128 + t], acc);
        lds.e.h[t] = fmaxf(acc, 0.f);
    }
    __syncthreads();
    if (t < 96) {
        float acc = b2[t];
        #pragma unroll 8
        for (int f = 0; f < 128; ++f) acc = fmaf(lds.e.h[f], W2[f*96 + t], acc);
        int q = (t/3) & 15;
        lds.e.ang[t] = tanhf(acc) * scaling[q] * PI_F;
    }
    __syncthreads();
    if (t < 32) {
        int l = t >> 4, q = t & 15;
        const float* a = lds.e.ang + l*48 + q*3;
        float st, ct, sp, cp, sl, cl;
        sincosf(a[0]*0.5f, &st, &ct);
        sincosf(a[1]*0.5f, &sp, &cp);
        sincosf(a[2]*0.5f, &sl, &cl);
        float2 A00 = make_float2( cp*ct,  sp*st);
        float2 A01 = make_float2(-sp*ct, -cp*st);
        float2 A10 = make_float2( sp*ct, -cp*st);
        float2 A11 = make_float2( cp*ct, -sp*st);
        float2 e0 = make_float2(cl, -sl), e1 = make_float2(cl, sl);
        v2f r00; r00.x = e0.x*A00.x - e0.y*A00.y; r00.y = e0.x*A00.y + e0.y*A00.x;
        v2f r01; r01.x = e0.x*A01.x - e0.y*A01.y; r01.y = e0.x*A01.y + e0.y*A01.x;
        v2f r10; r10.x = e1.x*A10.x - e1.y*A10.y; r10.y = e1.x*A10.y + e1.y*A10.x;
        v2f r11; r11.x = e1.x*A11.x - e1.y*A11.y; r11.y = e1.x*A11.y + e1.y*A11.x;
        if (l == 0) {                 // layer-0: U|0> = column 0
            lds.e.vL[q*2 + 0] = r00;
            lds.e.vL[q*2 + 1] = r10;
        } else {                      // layer-1 gates, row-major
            lds.e.uL[q*4 + 0] = r00; lds.e.uL[q*4 + 1] = r01;
            lds.e.uL[q*4 + 2] = r10; lds.e.uL[q*4 + 3] = r11;
        }
    }
    __syncthreads();
    // ---- chain phase: thread t = prefix (z0..z7) for L, suffix (z8..z15) for R ----
    #define AP(p, s) lds.e.vL[(15-(p))*2 + (s)]
    #define GG(p, zv, yv) lds.e.uL[(15-(p))*4 + (zv)*2 + (yv)]
    const float SL = 32.f;
    v2f Lg[2][2];   // [g][y7]
    {
        int z0 = t & 1, z1 = (t >> 1) & 1;
        #pragma unroll
        for (int g = 0; g < 2; ++g)
            #pragma unroll
            for (int y = 0; y < 2; ++y)
                Lg[g][y] = cmul(cmul(GG(0, z0, g), AP(0, g ^ y)), GG(1, z1, y));
        #pragma unroll
        for (int p = 2; p <= 7; ++p) {
            int zp = (t >> p) & 1;
            #pragma unroll
            for (int g = 0; g < 2; ++g) {
                v2f s0 = cmul(Lg[g][0], AP(p-1, 0)) + cmul(Lg[g][1], AP(p-1, 1));
                v2f s1 = cmul(Lg[g][0], AP(p-1, 1)) + cmul(Lg[g][1], AP(p-1, 0));
                Lg[g][0] = cmul(s0, GG(p, zp, 0));
                Lg[g][1] = cmul(s1, GG(p, zp, 1));
            }
        }
    }
    v2f Rg[2][2];   // [g][y7]
    {
        int z15 = (t >> 7) & 1;
        #pragma unroll
        for (int g = 0; g < 2; ++g)
            #pragma unroll
            for (int y14 = 0; y14 < 2; ++y14)
                Rg[g][y14] = cmul(cmul(AP(14, y14 ^ g),     AP(15, g)),     GG(15, z15, 0))
                           + cmul(cmul(AP(14, y14 ^ 1 ^ g), AP(15, 1 ^ g)), GG(15, z15, 1));
        #pragma unroll
        for (int p = 14; p >= 8; --p) {
            int zp = (t >> (p - 8)) & 1;
            #pragma unroll
            for (int g = 0; g < 2; ++g) {
                v2f t0 = cmul(GG(p, zp, 0), Rg[g][0]);
                v2f t1 = cmul(GG(p, zp, 1), Rg[g][1]);
                v2f n0 = cmul(AP(p-1, 0), t0) + cmul(AP(p-1, 1), t1);
                v2f n1 = cmul(AP(p-1, 1), t0) + cmul(AP(p-1, 0), t1);
                Rg[g][0] = n0; Rg[g][1] = n1;
            }
        }
    }
    #undef AP
    #undef GG
    // ---- pack fp16 rows into LDS: k = g*2 + y7; B-operand signs prebaked ----
    {
        float lre[4] = {Lg[0][0].x, Lg[0][1].x, Lg[1][0].x, Lg[1][1].x};
        float lim[4] = {Lg[0][0].y, Lg[0][1].y, Lg[1][0].y, Lg[1][1].y};
        float rre[4] = {Rg[0][0].x, Rg[0][1].x, Rg[1][0].x, Rg[1][1].x};
        float rim[4] = {Rg[0][0].y, Rg[0][1].y, Rg[1][0].y, Rg[1][1].y};
        H8 hre, him, hr;
        #pragma unroll
        for (int k = 0; k < 4; ++k) {
            hre.v[k]   = (_Float16)(SL * lre[k]);
            hre.v[4+k] = (_Float16)(-SL * lim[k]);
            him.v[k]   = (_Float16)(SL * lim[k]);
            him.v[4+k] = (_Float16)(SL * lre[k]);
            hr.v[k]    = (_Float16)(SL * rre[k]);
            hr.v[4+k]  = (_Float16)(SL * rim[k]);
        }
        *(int4*)&lds.e.lR[t*8]         = hr.i4;
        *(int4*)&lds.e.lL[t*8]         = hre.i4;   // re-plane col
        *(int4*)&lds.e.lL[(256+t)*8]   = him.i4;   // im-plane col
    }
    __syncthreads();
    // ---- amp phase: D[zh][zl|plane] = R @ L^T via MFMA (K=8 padded to 16) ----
    {
        const int wave = t >> 6, lane = t & 63, h2 = lane >> 5, l32 = lane & 31;
        f16x8 zf = {};
        _Float16* Aout = A + ((size_t)b << 16);
        #pragma unroll
        for (int mt2 = 0; mt2 < 2; ++mt2) {
            const int zh0 = (wave*2 + mt2)*32;
            f16x8 af = h2 ? zf : *(const f16x8*)&lds.e.lR[(zh0 + l32)*8];
            #pragma unroll
            for (int j = 0; j < 8; ++j) {
                f16x8 bre = h2 ? zf : *(const f16x8*)&lds.e.lL[(j*32 + l32)*8];
                f16x8 bim = h2 ? zf : *(const f16x8*)&lds.e.lL[(256 + j*32 + l32)*8];
                f32x16 zc = {};
                f32x16 dre = __builtin_amdgcn_mfma_f32_32x32x16_f16(af, bre, zc, 0, 0, 0);
                f32x16 dim = __builtin_amdgcn_mfma_f32_32x32x16_f16(af, bim, zc, 0, 0, 0);
                #pragma unroll
                for (int q = 0; q < 16; ++q) {
                    float p = fmaf(dre[q], dre[q], dim[q]*dim[q]) * 0.00390625f;  // 2^-8
                    int row = zh0 + 4*h2 + (q & 3) + 8*(q >> 2);
                    Aout[row*256 + j*32 + l32] = (_Float16)p;
                }
            }
        }
    }
}

// ---------------- K2: single-pass fp16 MFMA GEMM, split-K ----------------
// partial[ks][m][n] (bf16) = A[m, ks*256:+256] @ Wt[n, ks*256:+256]^T
// tile 128m x 128n x 256k, BK=64; grid (256 ks, 2 nt, 2 mt) = 1024 blocks.
__global__ __launch_bounds__(256, 4) void k_gemm(
        const _Float16* __restrict__ A, const _Float16* __restrict__ Bt,
        unsigned short* __restrict__ partial) {
    __shared__ _Float16 lA[128*64];   // [m][64k], row=128B=8 chunks, chunk c at c^(r&7)
    __shared__ _Float16 lB[128*64];
    const int ks = blockIdx.x, nt = blockIdx.y, mt = blockIdx.z;
    const int k0 = ks*256, n0 = nt*128, m0 = mt*128;
    const int tid = threadIdx.x, wave = tid >> 6, lane = tid & 63;
    const int mw = wave >> 1, nw = wave & 1;
    const int h = lane >> 5, l32 = lane & 31;
    f32x16 acc[2][2] = {};
    for (int s = 0; s < 4; ++s) {
        const int kb = k0 + s*64;
        #pragma unroll
        for (int i = 0; i < 4; ++i) {
            int ia = wave*4 + i;
            int r = ia*8 + (lane >> 3);
            int cch = (lane & 7) ^ (r & 7);
            gll16(A  + (size_t)(m0 + r)*65536 + kb + cch*8, &lA[ia*512]);
            gll16(Bt + (size_t)(n0 + r)*65536 + kb + cch*8, &lB[ia*512]);
        }
        __syncthreads();
        #pragma unroll
        for (int kk = 0; kk < 4; ++kk) {
            const int ch = kk*2 + h;
            f16x8 af[2], bf[2];
            #pragma unroll
            for (int xx = 0; xx < 2; ++xx) {
                int rA = mw*64 + xx*32 + l32;
                af[xx] = *(const f16x8*)&lA[rA*64 + ((ch ^ (rA & 7)) << 3)];
                int rB = nw*64 + xx*32 + l32;
                bf[xx] = *(const f16x8*)&lB[rB*64 + ((ch ^ (rB & 7)) << 3)];
            }
            #pragma unroll
            for (int i = 0; i < 2; ++i)
                #pragma unroll
                for (int jj = 0; jj < 2; ++jj)
                    acc[i][jj] = __builtin_amdgcn_mfma_f32_32x32x16_f16(af[i], bf[jj], acc[i][jj], 0, 0, 0);
        }
        __syncthreads();
    }
    unsigned short* pp = partial + (size_t)ks*65536;
    #pragma unroll
    for (int i = 0; i < 2; ++i) {
        #pragma unroll
        for (int jj = 0; jj < 2; ++jj) {
            int n = n0 + nw*64 + jj*32 + l32;
            int mb = m0 + mw*64 + i*32 + 4*h;
            #pragma unroll
            for (int q = 0; q < 16; ++q) {
                int m = mb + (q & 3) + 8*(q >> 2);
                pp[m*256 + n] = (unsigned short)f2bf_rn(acc[i][jj][q]);
            }
        }
    }
}

// ---------------- K3: stage-1 reduce: partial[256ks] -> partial2[8g] fp32 ----
__global__ __launch_bounds__(256) void k_red(
        const unsigned short* __restrict__ partial, float* __restrict__ partial2) {
    const int m = blockIdx.x & 255, g = blockIdx.x >> 8;   // grid 2048
    const int t = threadIdx.x;
    const unsigned short* p = partial + (size_t)(g*32)*65536 + m*256 + t;
    float s = 0.f;
    #pragma unroll 8
    for (int kc = 0; kc < 32; ++kc)
        s += __uint_as_float(((unsigned)p[(size_t)kc*65536]) << 16);
    partial2[((size_t)g*256 + m)*256 + t] = s;
}

// ---------------- K4: stage-2 reduce (x 2^-18) + bias + relu + GEMV ----
__global__ __launch_bounds__(256) void k_final(
        const float* __restrict__ partial2, const float* __restrict__ bd1,
        const float* __restrict__ Wd2, const float* __restrict__ bd2,
        float* __restrict__ out) {
    __shared__ float row[256];
    const int m = blockIdx.x, t = threadIdx.x;
    {
        float s = 0.f;
        #pragma unroll
        for (int g = 0; g < 8; ++g)
            s += partial2[((size_t)g*256 + m)*256 + t];
        const float SC = 1.f / 262144.f;   // undo 4096 (A) * 64 (Wt)
        row[t] = fmaxf(fmaf(s, SC, bd1[t]), 0.f);
    }
    __syncthreads();
    if (t < 64) {
        float o = bd2[t];
        #pragma unroll 8
        for (int n = 0; n < 256; ++n) o = fmaf(row[n], Wd2[n*64 + t], o);
        out[m*64 + t] = fmaxf(o, 0.f);
    }
}

extern "C" void kernel_launch(void* const* d_in, const int* in_sizes, int n_in,
                              void* d_out, int out_size, void* d_ws, size_t ws_size,
                              hipStream_t stream) {
    const float* x       = (const float*)d_in[0];
    const float* W1      = (const float*)d_in[1];
    const float* b1      = (const float*)d_in[2];
    const float* W2      = (const float*)d_in[3];
    const float* b2      = (const float*)d_in[4];
    const float* scaling = (const float*)d_in[5];
    const float* Wd1     = (const float*)d_in[6];
    const float* bd1     = (const float*)d_in[7];
    const float* Wd2     = (const float*)d_in[8];
    const float* bd2     = (const float*)d_in[9];
    float* out = (float*)d_out;

    char* ws = (char*)d_ws;
    const size_t MB = 1024*1024;
    _Float16* A  = (_Float16*)(ws + 4*MB);           // 32 MB  [4,36)
    _Float16* Wt = (_Float16*)(ws + 36*MB);          // 32 MB  [36,68)
    unsigned short* partial = (unsigned short*)(ws + 68*MB);  // 32 MB [68,100)
    float* partial2 = (float*)(ws + 100*MB);         //  2 MB  [100,102)

    hipLaunchKernelGGL(k_pre, dim3(1280), dim3(256), 0, stream,
                       x, W1, b1, W2, b2, scaling, Wd1, Wt, A);
    hipLaunchKernelGGL(k_gemm, dim3(256, 2, 2), dim3(256), 0, stream, A, Wt, partial);
    hipLaunchKernelGGL(k_red, dim3(2048), dim3(256), 0, stream, partial, partial2);
    hipLaunchKernelGGL(k_final, dim3(256), dim3(256), 0, stream,
                       partial2, bd1, Wd2, bd2, out);
}

// Round 8
// 170.102 us; speedup vs baseline: 2.7378x; 1.0136x over previous
//
#include <hip/hip_runtime.h>
#include <hip/hip_fp16.h>

#define PI_F 3.14159265358979323846f

typedef __attribute__((ext_vector_type(8))) _Float16 f16x8;
typedef __attribute__((ext_vector_type(16))) float f32x16;
typedef __attribute__((ext_vector_type(2))) float v2f;

// ---------- packed-fp32 complex helpers (v_pk_fma_f32) ----------
__device__ __forceinline__ v2f pfma(v2f a, v2f b, v2f c) {
    return __builtin_elementwise_fma(a, b, c);
}
__device__ __forceinline__ v2f vswap(v2f a) { return __builtin_shufflevector(a, a, 1, 0); }
__device__ __forceinline__ v2f vsplat(float x) { v2f r; r.x = x; r.y = x; return r; }
__device__ __forceinline__ v2f mkc(v2f u) { v2f r; r.x = -u.y; r.y = u.y; return r; }
__device__ __forceinline__ v2f cmul(v2f a, v2f b) {
    return pfma(mkc(a), vswap(b), vsplat(a.x) * b);
}

__device__ __forceinline__ unsigned f2bf_rn(float x) {
    unsigned u = __float_as_uint(x);
    return (u + 0x7fffu + ((u >> 16) & 1u)) >> 16;
}

union H8 { int4 i4; f16x8 v; };

// async global->LDS, 16B per lane; LDS dest = wave-uniform base + lane*16
__device__ __forceinline__ void gll16(const void* g, void* l) {
    __builtin_amdgcn_global_load_lds(
        (const __attribute__((address_space(1))) void*)g,
        (__attribute__((address_space(3))) void*)l, 16, 0, 0);
}

// ---------------- K1 fused: [blocks 0..255]  encoder -> U3 -> MPS chain -> amp MFMA -> A[b]
//                             [blocks 256..1279] Wd1 conv/transpose -> Wt ----------------
// amp(z) = sum_{g,y7} L(z0..z7)[g,y7] * R(z8..z15)[g,y7]  (bond 2 + y0 boundary)
union PreLds {
    struct {
        float xr[64]; float h[128]; float ang[96];
        v2f vL[32];            // a_p: vL[(15-p)*2 + s]
        v2f uL[64];            // G_p: uL[(15-p)*4 + z*2 + y]
        _Float16 lR[256*8];    // R rows (4 KB)
        _Float16 lL[512*8];    // L re-plane rows 0..255, im-plane 256..511 (8 KB)
    } e;
    _Float16 wt[64][260];      // conv transpose tile: 256 k-halfs + 4 pad (33.3 KB)
};

__global__ __launch_bounds__(256) void k_pre(
        const float* __restrict__ x, const float* __restrict__ W1,
        const float* __restrict__ b1, const float* __restrict__ W2,
        const float* __restrict__ b2, const float* __restrict__ scaling,
        const float* __restrict__ Wd1, _Float16* __restrict__ Wt,
        _Float16* __restrict__ A) {
    __shared__ PreLds lds;
    const int t = threadIdx.x;
    if (blockIdx.x >= 256) {
        // ---- conv: Wd1 [65536k][256n] fp32 -> Wt [256n][65536k] fp16 (x64 scale) ----
        // k-rows paired -> half2 packed ds_write_b32 (32 LDS writes/thread)
        const int cb = blockIdx.x - 256;         // 0..1023
        const int kb = (cb >> 2) * 256;          // k tile of 256
        const int nb = (cb & 3) * 64;            // n tile of 64
        unsigned* wtw = (unsigned*)&lds.wt[0][0];   // word view: row stride 130 words
        #pragma unroll
        for (int it = 0; it < 8; ++it) {
            int idx = t + it*256;                // 0..2047
            int kr2 = idx >> 4;                  // k-pair 0..127
            int nc4 = (idx & 15) * 4;
            const float* src = Wd1 + (size_t)(kb + 2*kr2)*256 + nb + nc4;
            float4 w0 = *(const float4*)src;
            float4 w1 = *(const float4*)(src + 256);
            #pragma unroll
            for (int j = 0; j < 4; ++j) {
                float a0 = (j==0?w0.x:j==1?w0.y:j==2?w0.z:w0.w) * 64.f;
                float a1 = (j==0?w1.x:j==1?w1.y:j==2?w1.z:w1.w) * 64.f;
                __half2 hh = __floats2half2_rn(a0, a1);
                unsigned u; __builtin_memcpy(&u, &hh, 4);
                wtw[(nc4 + j)*130 + kr2] = u;
            }
        }
        __syncthreads();
        // writes: per instruction 2 rows x 512B contiguous
        const int wv = t >> 6, ln = t & 63;
        const int u = ln & 31;                   // 16B unit within row
        #pragma unroll
        for (int r = 0; r < 8; ++r) {
            int n = r*8 + wv*2 + (ln >> 5);
            uint2 lo = *(const uint2*)&lds.wt[n][u*8];
            uint2 hi = *(const uint2*)&lds.wt[n][u*8 + 4];
            int4 hh = make_int4((int)lo.x, (int)lo.y, (int)hi.x, (int)hi.y);
            *(int4*)(Wt + ((size_t)(nb + n) << 16) + kb + u*8) = hh;
        }
        return;
    }
    // ---- encoder phase ----
    const int b = blockIdx.x;
    if (t < 64) lds.e.xr[t] = x[b*64 + t];
    __syncthreads();
    if (t < 128) {
        float acc = b1[t];
        #pragma unroll 8
        for (int f = 0; f < 64; ++f) acc = fmaf(lds.e.xr[f], W1[f*128 + t], acc);
        lds.e.h[t] = fmaxf(acc, 0.f);
    }
    __syncthreads();
    if (t < 96) {
        float acc = b2[t];
        #pragma unroll 8
        for (int f = 0; f < 128; ++f) acc = fmaf(lds.e.h[f], W2[f*96 + t], acc);
        int q = (t/3) & 15;
        lds.e.ang[t] = tanhf(acc) * scaling[q] * PI_F;
    }
    __syncthreads();
    if (t < 32) {
        int l = t >> 4, q = t & 15;
        const float* a = lds.e.ang + l*48 + q*3;
        float st, ct, sp, cp, sl, cl;
        sincosf(a[0]*0.5f, &st, &ct);
        sincosf(a[1]*0.5f, &sp, &cp);
        sincosf(a[2]*0.5f, &sl, &cl);
        float2 A00 = make_float2( cp*ct,  sp*st);
        float2 A01 = make_float2(-sp*ct, -cp*st);
        float2 A10 = make_float2( sp*ct, -cp*st);
        float2 A11 = make_float2( cp*ct, -sp*st);
        float2 e0 = make_float2(cl, -sl), e1 = make_float2(cl, sl);
        v2f r00; r00.x = e0.x*A00.x - e0.y*A00.y; r00.y = e0.x*A00.y + e0.y*A00.x;
        v2f r01; r01.x = e0.x*A01.x - e0.y*A01.y; r01.y = e0.x*A01.y + e0.y*A01.x;
        v2f r10; r10.x = e1.x*A10.x - e1.y*A10.y; r10.y = e1.x*A10.y + e1.y*A10.x;
        v2f r11; r11.x = e1.x*A11.x - e1.y*A11.y; r11.y = e1.x*A11.y + e1.y*A11.x;
        if (l == 0) {                 // layer-0: U|0> = column 0
            lds.e.vL[q*2 + 0] = r00;
            lds.e.vL[q*2 + 1] = r10;
        } else {                      // layer-1 gates, row-major
            lds.e.uL[q*4 + 0] = r00; lds.e.uL[q*4 + 1] = r01;
            lds.e.uL[q*4 + 2] = r10; lds.e.uL[q*4 + 3] = r11;
        }
    }
    __syncthreads();
    // ---- chain phase: thread t = prefix (z0..z7) for L, suffix (z8..z15) for R ----
    #define AP(p, s) lds.e.vL[(15-(p))*2 + (s)]
    #define GG(p, zv, yv) lds.e.uL[(15-(p))*4 + (zv)*2 + (yv)]
    const float SL = 32.f;
    v2f Lg[2][2];   // [g][y7]
    {
        int z0 = t & 1, z1 = (t >> 1) & 1;
        #pragma unroll
        for (int g = 0; g < 2; ++g)
            #pragma unroll
            for (int y = 0; y < 2; ++y)
                Lg[g][y] = cmul(cmul(GG(0, z0, g), AP(0, g ^ y)), GG(1, z1, y));
        #pragma unroll
        for (int p = 2; p <= 7; ++p) {
            int zp = (t >> p) & 1;
            #pragma unroll
            for (int g = 0; g < 2; ++g) {
                v2f s0 = cmul(Lg[g][0], AP(p-1, 0)) + cmul(Lg[g][1], AP(p-1, 1));
                v2f s1 = cmul(Lg[g][0], AP(p-1, 1)) + cmul(Lg[g][1], AP(p-1, 0));
                Lg[g][0] = cmul(s0, GG(p, zp, 0));
                Lg[g][1] = cmul(s1, GG(p, zp, 1));
            }
        }
    }
    v2f Rg[2][2];   // [g][y7]
    {
        int z15 = (t >> 7) & 1;
        #pragma unroll
        for (int g = 0; g < 2; ++g)
            #pragma unroll
            for (int y14 = 0; y14 < 2; ++y14)
                Rg[g][y14] = cmul(cmul(AP(14, y14 ^ g),     AP(15, g)),     GG(15, z15, 0))
                           + cmul(cmul(AP(14, y14 ^ 1 ^ g), AP(15, 1 ^ g)), GG(15, z15, 1));
        #pragma unroll
        for (int p = 14; p >= 8; --p) {
            int zp = (t >> (p - 8)) & 1;
            #pragma unroll
            for (int g = 0; g < 2; ++g) {
                v2f t0 = cmul(GG(p, zp, 0), Rg[g][0]);
                v2f t1 = cmul(GG(p, zp, 1), Rg[g][1]);
                v2f n0 = cmul(AP(p-1, 0), t0) + cmul(AP(p-1, 1), t1);
                v2f n1 = cmul(AP(p-1, 1), t0) + cmul(AP(p-1, 0), t1);
                Rg[g][0] = n0; Rg[g][1] = n1;
            }
        }
    }
    #undef AP
    #undef GG
    // ---- pack fp16 rows into LDS: k = g*2 + y7; B-operand signs prebaked ----
    {
        float lre[4] = {Lg[0][0].x, Lg[0][1].x, Lg[1][0].x, Lg[1][1].x};
        float lim[4] = {Lg[0][0].y, Lg[0][1].y, Lg[1][0].y, Lg[1][1].y};
        float rre[4] = {Rg[0][0].x, Rg[0][1].x, Rg[1][0].x, Rg[1][1].x};
        float rim[4] = {Rg[0][0].y, Rg[0][1].y, Rg[1][0].y, Rg[1][1].y};
        H8 hre, him, hr;
        #pragma unroll
        for (int k = 0; k < 4; ++k) {
            hre.v[k]   = (_Float16)(SL * lre[k]);
            hre.v[4+k] = (_Float16)(-SL * lim[k]);
            him.v[k]   = (_Float16)(SL * lim[k]);
            him.v[4+k] = (_Float16)(SL * lre[k]);
            hr.v[k]    = (_Float16)(SL * rre[k]);
            hr.v[4+k]  = (_Float16)(SL * rim[k]);
        }
        *(int4*)&lds.e.lR[t*8]         = hr.i4;
        *(int4*)&lds.e.lL[t*8]         = hre.i4;   // re-plane col
        *(int4*)&lds.e.lL[(256+t)*8]   = him.i4;   // im-plane col
    }
    __syncthreads();
    // ---- amp phase: D[zh][zl|plane] = R @ L^T via MFMA (K=8 padded to 16) ----
    {
        const int wave = t >> 6, lane = t & 63, h2 = lane >> 5, l32 = lane & 31;
        f16x8 zf = {};
        _Float16* Aout = A + ((size_t)b << 16);
        #pragma unroll
        for (int mt2 = 0; mt2 < 2; ++mt2) {
            const int zh0 = (wave*2 + mt2)*32;
            f16x8 af = h2 ? zf : *(const f16x8*)&lds.e.lR[(zh0 + l32)*8];
            #pragma unroll
            for (int j = 0; j < 8; ++j) {
                f16x8 bre = h2 ? zf : *(const f16x8*)&lds.e.lL[(j*32 + l32)*8];
                f16x8 bim = h2 ? zf : *(const f16x8*)&lds.e.lL[(256 + j*32 + l32)*8];
                f32x16 zc = {};
                f32x16 dre = __builtin_amdgcn_mfma_f32_32x32x16_f16(af, bre, zc, 0, 0, 0);
                f32x16 dim = __builtin_amdgcn_mfma_f32_32x32x16_f16(af, bim, zc, 0, 0, 0);
                #pragma unroll
                for (int q = 0; q < 16; ++q) {
                    float p = fmaf(dre[q], dre[q], dim[q]*dim[q]) * 0.00390625f;  // 2^-8
                    int row = zh0 + 4*h2 + (q & 3) + 8*(q >> 2);
                    Aout[row*256 + j*32 + l32] = (_Float16)p;
                }
            }
        }
    }
}

// ---------------- K2: single-pass fp16 MFMA GEMM, split-K, XCD-swizzled ----------------
// partial[ks][m][n] (bf16) = A[m, ks*512:+512] @ Wt[n, ks*512:+512]^T
// tile 128m x 128n x 512k, BK=64; grid 512 flat: id = (ks&7) + 8*((ks>>3)*4 + p)
// -> the 4 (nt,mt) blocks of one ks land on one XCD (id%8 = ks%8) for L2 reuse.
__global__ __launch_bounds__(256, 4) void k_gemm(
        const _Float16* __restrict__ A, const _Float16* __restrict__ Bt,
        unsigned short* __restrict__ partial) {
    __shared__ _Float16 lA[128*64];   // [m][64k], row=128B=8 chunks, chunk c at c^(r&7)
    __shared__ _Float16 lB[128*64];
    const int id = blockIdx.x;
    const int ks = (id & 7) | ((id >> 5) << 3);
    const int p  = (id >> 3) & 3;
    const int nt = p >> 1, mt = p & 1;
    const int k0 = ks*512, n0 = nt*128, m0 = mt*128;
    const int tid = threadIdx.x, wave = tid >> 6, lane = tid & 63;
    const int mw = wave >> 1, nw = wave & 1;
    const int h = lane >> 5, l32 = lane & 31;
    f32x16 acc[2][2] = {};
    for (int s = 0; s < 8; ++s) {
        const int kb = k0 + s*64;
        #pragma unroll
        for (int i = 0; i < 4; ++i) {
            int ia = wave*4 + i;
            int r = ia*8 + (lane >> 3);
            int cch = (lane & 7) ^ (r & 7);
            gll16(A  + (size_t)(m0 + r)*65536 + kb + cch*8, &lA[ia*512]);
            gll16(Bt + (size_t)(n0 + r)*65536 + kb + cch*8, &lB[ia*512]);
        }
        __syncthreads();
        #pragma unroll
        for (int kk = 0; kk < 4; ++kk) {
            const int ch = kk*2 + h;
            f16x8 af[2], bf[2];
            #pragma unroll
            for (int xx = 0; xx < 2; ++xx) {
                int rA = mw*64 + xx*32 + l32;
                af[xx] = *(const f16x8*)&lA[rA*64 + ((ch ^ (rA & 7)) << 3)];
                int rB = nw*64 + xx*32 + l32;
                bf[xx] = *(const f16x8*)&lB[rB*64 + ((ch ^ (rB & 7)) << 3)];
            }
            #pragma unroll
            for (int i = 0; i < 2; ++i)
                #pragma unroll
                for (int jj = 0; jj < 2; ++jj)
                    acc[i][jj] = __builtin_amdgcn_mfma_f32_32x32x16_f16(af[i], bf[jj], acc[i][jj], 0, 0, 0);
        }
        __syncthreads();
    }
    unsigned short* pp = partial + (size_t)ks*65536;
    #pragma unroll
    for (int i = 0; i < 2; ++i) {
        #pragma unroll
        for (int jj = 0; jj < 2; ++jj) {
            int n = n0 + nw*64 + jj*32 + l32;
            int mb = m0 + mw*64 + i*32 + 4*h;
            #pragma unroll
            for (int q = 0; q < 16; ++q) {
                int m = mb + (q & 3) + 8*(q >> 2);
                pp[m*256 + n] = (unsigned short)f2bf_rn(acc[i][jj][q]);
            }
        }
    }
}

// ---------------- K3: stage-1 reduce: partial[128ks] -> partial2[8g] fp32 ----
__global__ __launch_bounds__(256) void k_red(
        const unsigned short* __restrict__ partial, float* __restrict__ partial2) {
    const int m = blockIdx.x & 255, g = blockIdx.x >> 8;   // grid 2048
    const int t = threadIdx.x;
    const unsigned short* p = partial + (size_t)(g*16)*65536 + m*256 + t;
    float s = 0.f;
    #pragma unroll 16
    for (int kc = 0; kc < 16; ++kc)
        s += __uint_as_float(((unsigned)p[(size_t)kc*65536]) << 16);
    partial2[((size_t)g*256 + m)*256 + t] = s;
}

// ---------------- K4: stage-2 reduce (x 2^-18) + bias + relu + GEMV ----
__global__ __launch_bounds__(256) void k_final(
        const float* __restrict__ partial2, const float* __restrict__ bd1,
        const float* __restrict__ Wd2, const float* __restrict__ bd2,
        float* __restrict__ out) {
    __shared__ float row[256];
    const int m = blockIdx.x, t = threadIdx.x;
    {
        float s = 0.f;
        #pragma unroll
        for (int g = 0; g < 8; ++g)
            s += partial2[((size_t)g*256 + m)*256 + t];
        const float SC = 1.f / 262144.f;   // undo 4096 (A) * 64 (Wt)
        row[t] = fmaxf(fmaf(s, SC, bd1[t]), 0.f);
    }
    __syncthreads();
    if (t < 64) {
        float o = bd2[t];
        #pragma unroll 8
        for (int n = 0; n < 256; ++n) o = fmaf(row[n], Wd2[n*64 + t], o);
        out[m*64 + t] = fmaxf(o, 0.f);
    }
}

extern "C" void kernel_launch(void* const* d_in, const int* in_sizes, int n_in,
                              void* d_out, int out_size, void* d_ws, size_t ws_size,
                              hipStream_t stream) {
    const float* x       = (const float*)d_in[0];
    const float* W1      = (const float*)d_in[1];
    const float* b1      = (const float*)d_in[2];
    const float* W2      = (const float*)d_in[3];
    const float* b2      = (const float*)d_in[4];
    const float* scaling = (const float*)d_in[5];
    const float* Wd1     = (const float*)d_in[6];
    const float* bd1     = (const float*)d_in[7];
    const float* Wd2     = (const float*)d_in[8];
    const float* bd2     = (const float*)d_in[9];
    float* out = (float*)d_out;

    char* ws = (char*)d_ws;
    const size_t MB = 1024*1024;
    _Float16* A  = (_Float16*)(ws + 4*MB);           // 32 MB  [4,36)
    _Float16* Wt = (_Float16*)(ws + 36*MB);          // 32 MB  [36,68)
    unsigned short* partial = (unsigned short*)(ws + 68*MB);  // 16 MB [68,84)
    float* partial2 = (float*)(ws + 84*MB);          //  2 MB  [84,86)

    hipLaunchKernelGGL(k_pre, dim3(1280), dim3(256), 0, stream,
                       x, W1, b1, W2, b2, scaling, Wd1, Wt, A);
    hipLaunchKernelGGL(k_gemm, dim3(512), dim3(256), 0, stream, A, Wt, partial);
    hipLaunchKernelGGL(k_red, dim3(2048), dim3(256), 0, stream, partial, partial2);
    hipLaunchKernelGGL(k_final, dim3(256), dim3(256), 0, stream,
                       partial2, bd1, Wd2, bd2, out);
}

// Round 9
// 165.641 us; speedup vs baseline: 2.8115x; 1.0269x over previous
//
#include <hip/hip_runtime.h>
#include <hip/hip_fp16.h>

#define PI_F 3.14159265358979323846f

typedef __attribute__((ext_vector_type(8))) _Float16 f16x8;
typedef __attribute__((ext_vector_type(16))) float f32x16;
typedef __attribute__((ext_vector_type(2))) float v2f;

// ---------- packed-fp32 complex helpers (v_pk_fma_f32) ----------
__device__ __forceinline__ v2f pfma(v2f a, v2f b, v2f c) {
    return __builtin_elementwise_fma(a, b, c);
}
__device__ __forceinline__ v2f vswap(v2f a) { return __builtin_shufflevector(a, a, 1, 0); }
__device__ __forceinline__ v2f vsplat(float x) { v2f r; r.x = x; r.y = x; return r; }
__device__ __forceinline__ v2f mkc(v2f u) { v2f r; r.x = -u.y; r.y = u.y; return r; }
__device__ __forceinline__ v2f cmul(v2f a, v2f b) {
    return pfma(mkc(a), vswap(b), vsplat(a.x) * b);
}

__device__ __forceinline__ unsigned f2bf_rn(float x) {
    unsigned u = __float_as_uint(x);
    return (u + 0x7fffu + ((u >> 16) & 1u)) >> 16;
}

union H8 { int4 i4; f16x8 v; };

// async global->LDS, 16B per lane; LDS dest = wave-uniform base + lane*16
__device__ __forceinline__ void gll16(const void* g, void* l) {
    __builtin_amdgcn_global_load_lds(
        (const __attribute__((address_space(1))) void*)g,
        (__attribute__((address_space(3))) void*)l, 16, 0, 0);
}

// ---------------- K1 fused: [blocks 0..255]  encoder -> U3 -> MPS chain -> amp MFMA -> A[b]
//                             [blocks 256..2303] Wd1 conv/transpose -> Wt ----------------
// amp(z) = sum_{g,y7} L(z0..z7)[g,y7] * R(z8..z15)[g,y7]  (bond 2 + y0 boundary)
// LDS union kept <= 17 KB -> 9 blocks/CU (the R8 conv was latency-bound at 4 blocks/CU).
union PreLds {
    struct {
        float xr[64]; float h[128]; float ang[96];
        v2f vL[32];            // a_p: vL[(15-p)*2 + s]
        v2f uL[64];            // G_p: uL[(15-p)*4 + z*2 + y]
        _Float16 lR[256*8];    // R rows (4 KB)
        _Float16 lL[512*8];    // L re-plane rows 0..255, im-plane 256..511 (8 KB)
    } e;
    _Float16 wt[64][134];      // conv tile: 128 k-halfwords + 6 pad (16.75 KB)
};

__global__ __launch_bounds__(256) void k_pre(
        const float* __restrict__ x, const float* __restrict__ W1,
        const float* __restrict__ b1, const float* __restrict__ W2,
        const float* __restrict__ b2, const float* __restrict__ scaling,
        const float* __restrict__ Wd1, _Float16* __restrict__ Wt,
        _Float16* __restrict__ A) {
    __shared__ PreLds lds;
    const int t = threadIdx.x;
    if (blockIdx.x >= 256) {
        // ---- conv: Wd1 [65536k][256n] fp32 -> Wt [256n][65536k] fp16 (x64 scale) ----
        // tile 128k x 64n; k-rows paired -> packed half2 ds_write_b32
        const int cb = blockIdx.x - 256;         // 0..2047
        const int kb = (cb >> 2) * 128;          // 512 k-tiles
        const int nb = (cb & 3) * 64;            // 4 n-tiles
        unsigned* wtw = (unsigned*)&lds.wt[0][0];   // word view: row stride 67 words
        #pragma unroll
        for (int it = 0; it < 4; ++it) {
            int idx = t + it*256;                // 0..1023
            int kr2 = idx >> 4;                  // k-pair 0..63
            int nc4 = (idx & 15) * 4;
            const float* src = Wd1 + (size_t)(kb + 2*kr2)*256 + nb + nc4;
            float4 w0 = *(const float4*)src;
            float4 w1 = *(const float4*)(src + 256);
            #pragma unroll
            for (int j = 0; j < 4; ++j) {
                float a0 = (j==0?w0.x:j==1?w0.y:j==2?w0.z:w0.w) * 64.f;
                float a1 = (j==0?w1.x:j==1?w1.y:j==2?w1.z:w1.w) * 64.f;
                __half2 hh = __floats2half2_rn(a0, a1);
                unsigned u; __builtin_memcpy(&u, &hh, 4);
                wtw[(nc4 + j)*67 + kr2] = u;
            }
        }
        __syncthreads();
        // writes: lanes 0-15 cover one 256B row run; 4 rows per instruction
        #pragma unroll
        for (int it = 0; it < 4; ++it) {
            int idx = t + it*256;
            int n = idx >> 4, u = idx & 15;
            int4 hh = *(const int4*)&lds.wt[n][u*8];
            *(int4*)(Wt + ((size_t)(nb + n) << 16) + kb + u*8) = hh;
        }
        return;
    }
    // ---- encoder phase ----
    const int b = blockIdx.x;
    if (t < 64) lds.e.xr[t] = x[b*64 + t];
    __syncthreads();
    if (t < 128) {
        float acc = b1[t];
        #pragma unroll 8
        for (int f = 0; f < 64; ++f) acc = fmaf(lds.e.xr[f], W1[f*128 + t], acc);
        lds.e.h[t] = fmaxf(acc, 0.f);
    }
    __syncthreads();
    if (t < 96) {
        float acc = b2[t];
        #pragma unroll 8
        for (int f = 0; f < 128; ++f) acc = fmaf(lds.e.h[f], W2[f*96 + t], acc);
        int q = (t/3) & 15;
        lds.e.ang[t] = tanhf(acc) * scaling[q] * PI_F;
    }
    __syncthreads();
    if (t < 32) {
        int l = t >> 4, q = t & 15;
        const float* a = lds.e.ang + l*48 + q*3;
        float st, ct, sp, cp, sl, cl;
        sincosf(a[0]*0.5f, &st, &ct);
        sincosf(a[1]*0.5f, &sp, &cp);
        sincosf(a[2]*0.5f, &sl, &cl);
        float2 A00 = make_float2( cp*ct,  sp*st);
        float2 A01 = make_float2(-sp*ct, -cp*st);
        float2 A10 = make_float2( sp*ct, -cp*st);
        float2 A11 = make_float2( cp*ct, -sp*st);
        float2 e0 = make_float2(cl, -sl), e1 = make_float2(cl, sl);
        v2f r00; r00.x = e0.x*A00.x - e0.y*A00.y; r00.y = e0.x*A00.y + e0.y*A00.x;
        v2f r01; r01.x = e0.x*A01.x - e0.y*A01.y; r01.y = e0.x*A01.y + e0.y*A01.x;
        v2f r10; r10.x = e1.x*A10.x - e1.y*A10.y; r10.y = e1.x*A10.y + e1.y*A10.x;
        v2f r11; r11.x = e1.x*A11.x - e1.y*A11.y; r11.y = e1.x*A11.y + e1.y*A11.x;
        if (l == 0) {                 // layer-0: U|0> = column 0
            lds.e.vL[q*2 + 0] = r00;
            lds.e.vL[q*2 + 1] = r10;
        } else {                      // layer-1 gates, row-major
            lds.e.uL[q*4 + 0] = r00; lds.e.uL[q*4 + 1] = r01;
            lds.e.uL[q*4 + 2] = r10; lds.e.uL[q*4 + 3] = r11;
        }
    }
    __syncthreads();
    // ---- chain phase: thread t = prefix (z0..z7) for L, suffix (z8..z15) for R ----
    #define AP(p, s) lds.e.vL[(15-(p))*2 + (s)]
    #define GG(p, zv, yv) lds.e.uL[(15-(p))*4 + (zv)*2 + (yv)]
    const float SL = 32.f;
    v2f Lg[2][2];   // [g][y7]
    {
        int z0 = t & 1, z1 = (t >> 1) & 1;
        #pragma unroll
        for (int g = 0; g < 2; ++g)
            #pragma unroll
            for (int y = 0; y < 2; ++y)
                Lg[g][y] = cmul(cmul(GG(0, z0, g), AP(0, g ^ y)), GG(1, z1, y));
        #pragma unroll
        for (int p = 2; p <= 7; ++p) {
            int zp = (t >> p) & 1;
            #pragma unroll
            for (int g = 0; g < 2; ++g) {
                v2f s0 = cmul(Lg[g][0], AP(p-1, 0)) + cmul(Lg[g][1], AP(p-1, 1));
                v2f s1 = cmul(Lg[g][0], AP(p-1, 1)) + cmul(Lg[g][1], AP(p-1, 0));
                Lg[g][0] = cmul(s0, GG(p, zp, 0));
                Lg[g][1] = cmul(s1, GG(p, zp, 1));
            }
        }
    }
    v2f Rg[2][2];   // [g][y7]
    {
        int z15 = (t >> 7) & 1;
        #pragma unroll
        for (int g = 0; g < 2; ++g)
            #pragma unroll
            for (int y14 = 0; y14 < 2; ++y14)
                Rg[g][y14] = cmul(cmul(AP(14, y14 ^ g),     AP(15, g)),     GG(15, z15, 0))
                           + cmul(cmul(AP(14, y14 ^ 1 ^ g), AP(15, 1 ^ g)), GG(15, z15, 1));
        #pragma unroll
        for (int p = 14; p >= 8; --p) {
            int zp = (t >> (p - 8)) & 1;
            #pragma unroll
            for (int g = 0; g < 2; ++g) {
                v2f t0 = cmul(GG(p, zp, 0), Rg[g][0]);
                v2f t1 = cmul(GG(p, zp, 1), Rg[g][1]);
                v2f n0 = cmul(AP(p-1, 0), t0) + cmul(AP(p-1, 1), t1);
                v2f n1 = cmul(AP(p-1, 1), t0) + cmul(AP(p-1, 0), t1);
                Rg[g][0] = n0; Rg[g][1] = n1;
            }
        }
    }
    #undef AP
    #undef GG
    // ---- pack fp16 rows into LDS: k = g*2 + y7; B-operand signs prebaked ----
    {
        float lre[4] = {Lg[0][0].x, Lg[0][1].x, Lg[1][0].x, Lg[1][1].x};
        float lim[4] = {Lg[0][0].y, Lg[0][1].y, Lg[1][0].y, Lg[1][1].y};
        float rre[4] = {Rg[0][0].x, Rg[0][1].x, Rg[1][0].x, Rg[1][1].x};
        float rim[4] = {Rg[0][0].y, Rg[0][1].y, Rg[1][0].y, Rg[1][1].y};
        H8 hre, him, hr;
        #pragma unroll
        for (int k = 0; k < 4; ++k) {
            hre.v[k]   = (_Float16)(SL * lre[k]);
            hre.v[4+k] = (_Float16)(-SL * lim[k]);
            him.v[k]   = (_Float16)(SL * lim[k]);
            him.v[4+k] = (_Float16)(SL * lre[k]);
            hr.v[k]    = (_Float16)(SL * rre[k]);
            hr.v[4+k]  = (_Float16)(SL * rim[k]);
        }
        *(int4*)&lds.e.lR[t*8]         = hr.i4;
        *(int4*)&lds.e.lL[t*8]         = hre.i4;   // re-plane col
        *(int4*)&lds.e.lL[(256+t)*8]   = him.i4;   // im-plane col
    }
    __syncthreads();
    // ---- amp phase: D[zh][zl|plane] = R @ L^T via MFMA (K=8 padded to 16) ----
    {
        const int wave = t >> 6, lane = t & 63, h2 = lane >> 5, l32 = lane & 31;
        f16x8 zf = {};
        _Float16* Aout = A + ((size_t)b << 16);
        #pragma unroll
        for (int mt2 = 0; mt2 < 2; ++mt2) {
            const int zh0 = (wave*2 + mt2)*32;
            f16x8 af = h2 ? zf : *(const f16x8*)&lds.e.lR[(zh0 + l32)*8];
            #pragma unroll
            for (int j = 0; j < 8; ++j) {
                f16x8 bre = h2 ? zf : *(const f16x8*)&lds.e.lL[(j*32 + l32)*8];
                f16x8 bim = h2 ? zf : *(const f16x8*)&lds.e.lL[(256 + j*32 + l32)*8];
                f32x16 zc = {};
                f32x16 dre = __builtin_amdgcn_mfma_f32_32x32x16_f16(af, bre, zc, 0, 0, 0);
                f32x16 dim = __builtin_amdgcn_mfma_f32_32x32x16_f16(af, bim, zc, 0, 0, 0);
                #pragma unroll
                for (int q = 0; q < 16; ++q) {
                    float p = fmaf(dre[q], dre[q], dim[q]*dim[q]) * 0.00390625f;  // 2^-8
                    int row = zh0 + 4*h2 + (q & 3) + 8*(q >> 2);
                    Aout[row*256 + j*32 + l32] = (_Float16)p;
                }
            }
        }
    }
}

// ---------------- K2: single-pass fp16 MFMA GEMM, split-K, XCD-swizzled ----------------
// partial[ks][m][n] (bf16) = A[m, ks*256:+256] @ Wt[n, ks*256:+256]^T
// tile 128m x 128n x 256k, BK=64; grid 1024 (4 blocks/CU): the 4 (nt,mt) blocks of one
// ks share id%8 -> same XCD -> 2nd read of each A/Wt half is an XCD-L2 hit.
__global__ __launch_bounds__(256, 4) void k_gemm(
        const _Float16* __restrict__ A, const _Float16* __restrict__ Bt,
        unsigned short* __restrict__ partial) {
    __shared__ _Float16 lA[128*64];   // [m][64k], row=128B=8 chunks, chunk c at c^(r&7)
    __shared__ _Float16 lB[128*64];
    const int id = blockIdx.x;
    const int ks = (id & 7) | ((id >> 5) << 3);
    const int p  = (id >> 3) & 3;
    const int nt = p >> 1, mt = p & 1;
    const int k0 = ks*256, n0 = nt*128, m0 = mt*128;
    const int tid = threadIdx.x, wave = tid >> 6, lane = tid & 63;
    const int mw = wave >> 1, nw = wave & 1;
    const int h = lane >> 5, l32 = lane & 31;
    f32x16 acc[2][2] = {};
    for (int s = 0; s < 4; ++s) {
        const int kb = k0 + s*64;
        #pragma unroll
        for (int i = 0; i < 4; ++i) {
            int ia = wave*4 + i;
            int r = ia*8 + (lane >> 3);
            int cch = (lane & 7) ^ (r & 7);
            gll16(A  + (size_t)(m0 + r)*65536 + kb + cch*8, &lA[ia*512]);
            gll16(Bt + (size_t)(n0 + r)*65536 + kb + cch*8, &lB[ia*512]);
        }
        __syncthreads();
        #pragma unroll
        for (int kk = 0; kk < 4; ++kk) {
            const int ch = kk*2 + h;
            f16x8 af[2], bf[2];
            #pragma unroll
            for (int xx = 0; xx < 2; ++xx) {
                int rA = mw*64 + xx*32 + l32;
                af[xx] = *(const f16x8*)&lA[rA*64 + ((ch ^ (rA & 7)) << 3)];
                int rB = nw*64 + xx*32 + l32;
                bf[xx] = *(const f16x8*)&lB[rB*64 + ((ch ^ (rB & 7)) << 3)];
            }
            #pragma unroll
            for (int i = 0; i < 2; ++i)
                #pragma unroll
                for (int jj = 0; jj < 2; ++jj)
                    acc[i][jj] = __builtin_amdgcn_mfma_f32_32x32x16_f16(af[i], bf[jj], acc[i][jj], 0, 0, 0);
        }
        __syncthreads();
    }
    unsigned short* pp = partial + (size_t)ks*65536;
    #pragma unroll
    for (int i = 0; i < 2; ++i) {
        #pragma unroll
        for (int jj = 0; jj < 2; ++jj) {
            int n = n0 + nw*64 + jj*32 + l32;
            int mb = m0 + mw*64 + i*32 + 4*h;
            #pragma unroll
            for (int q = 0; q < 16; ++q) {
                int m = mb + (q & 3) + 8*(q >> 2);
                pp[m*256 + n] = (unsigned short)f2bf_rn(acc[i][jj][q]);
            }
        }
    }
}

// ---------------- K3: fused reduce (256 ks, x 2^-18) + bias + relu + GEMV ----
__global__ __launch_bounds__(256) void k_final(
        const unsigned short* __restrict__ partial, const float* __restrict__ bd1,
        const float* __restrict__ Wd2, const float* __restrict__ bd2,
        float* __restrict__ out) {
    __shared__ float row[256];
    const int m = blockIdx.x, t = threadIdx.x;
    {
        const unsigned short* p = partial + m*256 + t;
        float s = 0.f;
        #pragma unroll 32
        for (int kc = 0; kc < 256; ++kc)
            s += __uint_as_float(((unsigned)p[(size_t)kc*65536]) << 16);
        const float SC = 1.f / 262144.f;   // undo 4096 (A) * 64 (Wt)
        row[t] = fmaxf(fmaf(s, SC, bd1[t]), 0.f);
    }
    __syncthreads();
    if (t < 64) {
        float o = bd2[t];
        #pragma unroll 8
        for (int n = 0; n < 256; ++n) o = fmaf(row[n], Wd2[n*64 + t], o);
        out[m*64 + t] = fmaxf(o, 0.f);
    }
}

extern "C" void kernel_launch(void* const* d_in, const int* in_sizes, int n_in,
                              void* d_out, int out_size, void* d_ws, size_t ws_size,
                              hipStream_t stream) {
    const float* x       = (const float*)d_in[0];
    const float* W1      = (const float*)d_in[1];
    const float* b1      = (const float*)d_in[2];
    const float* W2      = (const float*)d_in[3];
    const float* b2      = (const float*)d_in[4];
    const float* scaling = (const float*)d_in[5];
    const float* Wd1     = (const float*)d_in[6];
    const float* bd1     = (const float*)d_in[7];
    const float* Wd2     = (const float*)d_in[8];
    const float* bd2     = (const float*)d_in[9];
    float* out = (float*)d_out;

    char* ws = (char*)d_ws;
    const size_t MB = 1024*1024;
    _Float16* A  = (_Float16*)(ws + 4*MB);           // 32 MB  [4,36)
    _Float16* Wt = (_Float16*)(ws + 36*MB);          // 32 MB  [36,68)
    unsigned short* partial = (unsigned short*)(ws + 68*MB);  // 32 MB [68,100)

    hipLaunchKernelGGL(k_pre, dim3(2304), dim3(256), 0, stream,
                       x, W1, b1, W2, b2, scaling, Wd1, Wt, A);
    hipLaunchKernelGGL(k_gemm, dim3(1024), dim3(256), 0, stream, A, Wt, partial);
    hipLaunchKernelGGL(k_final, dim3(256), dim3(256), 0, stream,
                       partial, bd1, Wd2, bd2, out);
}